// Round 1
// baseline (6515.582 us; speedup 1.0000x reference)
//
#include <hip/hip_runtime.h>
#include <math.h>

// Problem constants (fixed by setup_inputs)
constexpr int Bb  = 2;
constexpr int Nn  = 1280;
constexpr int Cc  = 1024;
constexpr int Hh  = 16;
constexpr int DH  = 64;
constexpr int Ii  = 4096;
constexpr int Tt  = 256;    // text_len
constexpr int BSz = 128;    // block_size
constexpr int L1  = 4;      // len1
constexpr int Mrows = Bb * Nn;  // 2560

__device__ __forceinline__ int segof(int n) {
    return n < Tt ? 0 : (n < Tt + L1 * BSz ? 1 : 2);
}

// ---------------------------------------------------------------------------
// RMSNorm: one block per row, 256 threads, C=1024 (one float4 per thread)
// ---------------------------------------------------------------------------
__global__ __launch_bounds__(256)
void rms_kernel(const float* __restrict__ in, const float* __restrict__ w,
                float* __restrict__ out) {
    int row = blockIdx.x;                 // 0..M-1
    int n   = row % Nn;
    int seg = segof(n);
    const float* x = in + (size_t)row * Cc;
    int t = threadIdx.x;
    float4 xv = reinterpret_cast<const float4*>(x)[t];
    float ss = xv.x * xv.x + xv.y * xv.y + xv.z * xv.z + xv.w * xv.w;
#pragma unroll
    for (int off = 32; off; off >>= 1) ss += __shfl_down(ss, off, 64);
    __shared__ float red[4];
    __shared__ float s_r;
    int lane = t & 63, wid = t >> 6;
    if (lane == 0) red[wid] = ss;
    __syncthreads();
    if (t == 0) s_r = rsqrtf((red[0] + red[1] + red[2] + red[3]) * (1.0f / Cc) + 1e-6f);
    __syncthreads();
    float r = s_r;
    float4 wv = reinterpret_cast<const float4*>(w + (size_t)seg * Cc)[t];
    float4 ov;
    ov.x = wv.x * xv.x * r;
    ov.y = wv.y * xv.y * r;
    ov.z = wv.z * xv.z * r;
    ov.w = wv.w * xv.w * r;
    reinterpret_cast<float4*>(out + (size_t)row * Cc)[t] = ov;
}

// ---------------------------------------------------------------------------
// Generic segment-indexed fp32 GEMM: out[M x Nd] = A[M x K] @ W[seg][K x Nd]
// (+ bias[seg][Nd]) (+ res[M x Nd]).  64x64 tile, 256 thr, 4x4 microtile.
// Row tiles never cross segment boundaries (all multiples of 64).
// ---------------------------------------------------------------------------
template <bool BIAS, bool RES>
__global__ __launch_bounds__(256)
void gemm_seg(const float* __restrict__ A, const float* __restrict__ W,
              const float* __restrict__ bias, const float* __restrict__ res,
              float* __restrict__ out, int K, int Nd) {
    int rb  = blockIdx.x * 64, cb = blockIdx.y * 64;
    int seg = segof(rb % Nn);
    const float* Wp = W + (size_t)seg * K * Nd;
    __shared__ float As[16][68];   // padded, 16B-aligned rows
    __shared__ float Bs2[16][64];
    int tid = threadIdx.x;
    int tx = tid & 15, ty = tid >> 4;
    float acc[4][4] = {};
    for (int kt = 0; kt < K; kt += 16) {
#pragma unroll
        for (int i = 0; i < 4; i++) {
            int idx = tid + i * 256;
            As[idx & 15][idx >> 4] =
                A[(size_t)(rb + (idx >> 4)) * K + kt + (idx & 15)];
        }
#pragma unroll
        for (int i = 0; i < 4; i++) {
            int idx = tid + i * 256;
            Bs2[idx >> 6][idx & 63] =
                Wp[(size_t)(kt + (idx >> 6)) * Nd + cb + (idx & 63)];
        }
        __syncthreads();
#pragma unroll
        for (int kk = 0; kk < 16; kk++) {
            float4 av = *reinterpret_cast<const float4*>(&As[kk][ty * 4]);
            float4 bv = *reinterpret_cast<const float4*>(&Bs2[kk][tx * 4]);
            acc[0][0] += av.x * bv.x; acc[0][1] += av.x * bv.y;
            acc[0][2] += av.x * bv.z; acc[0][3] += av.x * bv.w;
            acc[1][0] += av.y * bv.x; acc[1][1] += av.y * bv.y;
            acc[1][2] += av.y * bv.z; acc[1][3] += av.y * bv.w;
            acc[2][0] += av.z * bv.x; acc[2][1] += av.z * bv.y;
            acc[2][2] += av.z * bv.z; acc[2][3] += av.z * bv.w;
            acc[3][0] += av.w * bv.x; acc[3][1] += av.w * bv.y;
            acc[3][2] += av.w * bv.z; acc[3][3] += av.w * bv.w;
        }
        __syncthreads();
    }
#pragma unroll
    for (int i = 0; i < 4; i++) {
        int r = rb + ty * 4 + i;
        float4 v = make_float4(acc[i][0], acc[i][1], acc[i][2], acc[i][3]);
        if (BIAS) {
            float4 bv = *reinterpret_cast<const float4*>(bias + (size_t)seg * Nd + cb + tx * 4);
            v.x += bv.x; v.y += bv.y; v.z += bv.z; v.w += bv.w;
        }
        if (RES) {
            float4 rv = *reinterpret_cast<const float4*>(res + (size_t)r * Nd + cb + tx * 4);
            v.x += rv.x; v.y += rv.y; v.z += rv.z; v.w += rv.w;
        }
        *reinterpret_cast<float4*>(out + (size_t)r * Nd + cb + tx * 4) = v;
    }
}

// ---------------------------------------------------------------------------
// Fused gate/up GEMM + SiLU:  t = silu(y @ gate_w[seg]) * (y @ up_w[seg])
// K = C = 1024, Nd = I = 4096
// ---------------------------------------------------------------------------
__global__ __launch_bounds__(256)
void gemm_gateup(const float* __restrict__ A, const float* __restrict__ G,
                 const float* __restrict__ U, float* __restrict__ out) {
    const int K = Cc, Nd = Ii;
    int rb  = blockIdx.x * 64, cb = blockIdx.y * 64;
    int seg = segof(rb % Nn);
    const float* Gp = G + (size_t)seg * K * Nd;
    const float* Up = U + (size_t)seg * K * Nd;
    __shared__ float As[16][68];
    __shared__ float Gs[16][64];
    __shared__ float Us[16][64];
    int tid = threadIdx.x;
    int tx = tid & 15, ty = tid >> 4;
    float accG[4][4] = {}, accU[4][4] = {};
    for (int kt = 0; kt < K; kt += 16) {
#pragma unroll
        for (int i = 0; i < 4; i++) {
            int idx = tid + i * 256;
            As[idx & 15][idx >> 4] =
                A[(size_t)(rb + (idx >> 4)) * K + kt + (idx & 15)];
        }
#pragma unroll
        for (int i = 0; i < 4; i++) {
            int idx = tid + i * 256;
            size_t woff = (size_t)(kt + (idx >> 6)) * Nd + cb + (idx & 63);
            Gs[idx >> 6][idx & 63] = Gp[woff];
            Us[idx >> 6][idx & 63] = Up[woff];
        }
        __syncthreads();
#pragma unroll
        for (int kk = 0; kk < 16; kk++) {
            float4 av = *reinterpret_cast<const float4*>(&As[kk][ty * 4]);
            float4 gv = *reinterpret_cast<const float4*>(&Gs[kk][tx * 4]);
            float4 uv = *reinterpret_cast<const float4*>(&Us[kk][tx * 4]);
            accG[0][0] += av.x * gv.x; accG[0][1] += av.x * gv.y;
            accG[0][2] += av.x * gv.z; accG[0][3] += av.x * gv.w;
            accG[1][0] += av.y * gv.x; accG[1][1] += av.y * gv.y;
            accG[1][2] += av.y * gv.z; accG[1][3] += av.y * gv.w;
            accG[2][0] += av.z * gv.x; accG[2][1] += av.z * gv.y;
            accG[2][2] += av.z * gv.z; accG[2][3] += av.z * gv.w;
            accG[3][0] += av.w * gv.x; accG[3][1] += av.w * gv.y;
            accG[3][2] += av.w * gv.z; accG[3][3] += av.w * gv.w;
            accU[0][0] += av.x * uv.x; accU[0][1] += av.x * uv.y;
            accU[0][2] += av.x * uv.z; accU[0][3] += av.x * uv.w;
            accU[1][0] += av.y * uv.x; accU[1][1] += av.y * uv.y;
            accU[1][2] += av.y * uv.z; accU[1][3] += av.y * uv.w;
            accU[2][0] += av.z * uv.x; accU[2][1] += av.z * uv.y;
            accU[2][2] += av.z * uv.z; accU[2][3] += av.z * uv.w;
            accU[3][0] += av.w * uv.x; accU[3][1] += av.w * uv.y;
            accU[3][2] += av.w * uv.z; accU[3][3] += av.w * uv.w;
        }
        __syncthreads();
    }
#pragma unroll
    for (int i = 0; i < 4; i++) {
        int r = rb + ty * 4 + i;
        float4 v;
        float g0 = accG[i][0], g1 = accG[i][1], g2 = accG[i][2], g3 = accG[i][3];
        v.x = g0 / (1.f + expf(-g0)) * accU[i][0];
        v.y = g1 / (1.f + expf(-g1)) * accU[i][1];
        v.z = g2 / (1.f + expf(-g2)) * accU[i][2];
        v.w = g3 / (1.f + expf(-g3)) * accU[i][3];
        *reinterpret_cast<float4*>(out + (size_t)r * Ii + cb + tx * 4) = v;
    }
}

// ---------------------------------------------------------------------------
// Split qkv + per-head q/k RMSNorm + RoPE.  One block per (b,n); 4 waves,
// each wave handles 4 heads; lane = dh.
// Output layout: (b*H+h, n, dh)
// ---------------------------------------------------------------------------
__global__ __launch_bounds__(256)
void split_rope(const float* __restrict__ qkv, const float* __restrict__ qn_w,
                const float* __restrict__ kn_w, const int* __restrict__ pos_ids,
                const int* __restrict__ tpos_ids, float* __restrict__ Q,
                float* __restrict__ K, float* __restrict__ V) {
    int row = blockIdx.x;   // b*N + n
    int b = row / Nn, n = row % Nn;
    int seg = segof(n);
    int lane = threadIdx.x & 63, wid = threadIdx.x >> 6;
    int pos = (n < Tt) ? tpos_ids[n] : pos_ids[n - Tt];
    int j = lane & 31;
    // inv = 10000^(-j/32); log2(10000) = 13.287712379549449
    float ang = (float)pos * exp2f(-(float)j * (13.287712379549449f / 32.f));
    float cv = cosf(ang), sv = sinf(ang);
    float qw = qn_w[seg * DH + lane], kw = kn_w[seg * DH + lane];
    for (int h = wid; h < Hh; h += 4) {
        const float* base = qkv + (size_t)row * (3 * Cc) + h * DH + lane;
        float q = base[0], k = base[Cc], v = base[2 * Cc];
        float qs = q * q, ks = k * k;
#pragma unroll
        for (int off = 32; off; off >>= 1) {
            qs += __shfl_xor(qs, off, 64);
            ks += __shfl_xor(ks, off, 64);
        }
        q = q * rsqrtf(qs * (1.f / DH) + 1e-6f) * qw;
        k = k * rsqrtf(ks * (1.f / DH) + 1e-6f) * kw;
        float qp = __shfl_xor(q, 32, 64);
        float kp = __shfl_xor(k, 32, 64);
        float qo = q * cv + ((lane < 32) ? -qp * sv : qp * sv);
        float ko = k * cv + ((lane < 32) ? -kp * sv : kp * sv);
        size_t oidx = ((size_t)(b * Hh + h) * Nn + n) * DH + lane;
        Q[oidx] = qo;
        K[oidx] = ko;
        V[oidx] = v;
    }
}

// ---------------------------------------------------------------------------
// Flash-style attention with analytic skip-causal mask.
// Grid (N/64, B*H), 64 threads (1 wave). Each lane owns one q row.
// K/V tiles (64x64) staged in LDS; scores in reg chunks of 16.
// Output layout: (B, N, C) so proj GEMM consumes it directly.
// ---------------------------------------------------------------------------
__global__ __launch_bounds__(64, 1)
void attn_kernel(const float* __restrict__ Qg, const float* __restrict__ Kg,
                 const float* __restrict__ Vg, float* __restrict__ O) {
    int qt = blockIdx.x;          // q tile
    int bh = blockIdx.y;          // b*H + h
    int b = bh >> 4, h = bh & 15;
    int lane = threadIdx.x;
    __shared__ float k_lds[64][64];
    __shared__ float v_lds[64][64];
    const size_t headoff = (size_t)bh * Nn * DH;
    int qi = qt * 64 + lane;
    float qreg[64];
#pragma unroll
    for (int d4 = 0; d4 < 16; d4++) {
        float4 t4 = *reinterpret_cast<const float4*>(&Qg[headoff + (size_t)qi * DH + d4 * 4]);
        qreg[d4 * 4 + 0] = t4.x; qreg[d4 * 4 + 1] = t4.y;
        qreg[d4 * 4 + 2] = t4.z; qreg[d4 * 4 + 3] = t4.w;
    }
    bool iq = qi >= Tt;
    int qb = iq ? (qi - Tt) / BSz : 0;
    float m = -3.4e38f, l = 0.f;
    float o[64];
#pragma unroll
    for (int d = 0; d < 64; d++) o[d] = 0.f;

    for (int kt2 = 0; kt2 < Nn / 64; kt2++) {
        __syncthreads();
#pragma unroll
        for (int p = 0; p < 16; p++) {
            int e = p * 64 + lane;
            int r = e >> 4, c = (e & 15) * 4;
            *reinterpret_cast<float4*>(&k_lds[r][c]) =
                *reinterpret_cast<const float4*>(&Kg[headoff + (size_t)(kt2 * 64 + r) * DH + c]);
            *reinterpret_cast<float4*>(&v_lds[r][c]) =
                *reinterpret_cast<const float4*>(&Vg[headoff + (size_t)(kt2 * 64 + r) * DH + c]);
        }
        __syncthreads();
        for (int kc = 0; kc < 4; kc++) {
            float s[16];
#pragma unroll
            for (int kk = 0; kk < 16; kk++) {
                int kkk = kc * 16 + kk;
                float4 accv = make_float4(0.f, 0.f, 0.f, 0.f);
#pragma unroll
                for (int d4 = 0; d4 < 16; d4++) {
                    float4 kv = *reinterpret_cast<const float4*>(&k_lds[kkk][d4 * 4]);
                    accv.x += qreg[d4 * 4 + 0] * kv.x;
                    accv.y += qreg[d4 * 4 + 1] * kv.y;
                    accv.z += qreg[d4 * 4 + 2] * kv.z;
                    accv.w += qreg[d4 * 4 + 3] * kv.w;
                }
                float acc = (accv.x + accv.y) + (accv.z + accv.w);
                int ki = kt2 * 64 + kc * 16 + kk;
                bool ik = ki >= Tt;
                int kb = ik ? (ki - Tt) / BSz : 0;
                bool mask = (!ik && qi >= ki) ||
                            (iq && ik && ((qb < L1 && kb < L1 && qb >= kb) ||
                                          (qb >= L1 && kb < L1 && qb - L1 > kb) ||
                                          (qb == kb)));
                s[kk] = mask ? acc * 0.125f : -3.4e38f;
            }
            float tmax = s[0];
#pragma unroll
            for (int kk = 1; kk < 16; kk++) tmax = fmaxf(tmax, s[kk]);
            if (tmax > -1e38f) {
                float mnew = fmaxf(m, tmax);
                float sc = __expf(m - mnew);
                l *= sc;
#pragma unroll
                for (int d = 0; d < 64; d++) o[d] *= sc;
#pragma unroll
                for (int kk = 0; kk < 16; kk++) {
                    float p = __expf(s[kk] - mnew);
                    l += p;
#pragma unroll
                    for (int d4 = 0; d4 < 16; d4++) {
                        float4 vv = *reinterpret_cast<const float4*>(&v_lds[kc * 16 + kk][d4 * 4]);
                        o[d4 * 4 + 0] += p * vv.x;
                        o[d4 * 4 + 1] += p * vv.y;
                        o[d4 * 4 + 2] += p * vv.z;
                        o[d4 * 4 + 3] += p * vv.w;
                    }
                }
                m = mnew;
            }
        }
    }
    float inv = 1.f / l;
#pragma unroll
    for (int d4 = 0; d4 < 16; d4++) {
        float4 w4 = make_float4(o[d4 * 4 + 0] * inv, o[d4 * 4 + 1] * inv,
                                o[d4 * 4 + 2] * inv, o[d4 * 4 + 3] * inv);
        *reinterpret_cast<float4*>(&O[((size_t)b * Nn + qi) * Cc + h * DH + d4 * 4]) = w4;
    }
}

// ---------------------------------------------------------------------------
// kernel_launch
// ---------------------------------------------------------------------------
extern "C" void kernel_launch(void* const* d_in, const int* in_sizes, int n_in,
                              void* d_out, int out_size, void* d_ws, size_t ws_size,
                              hipStream_t stream) {
    const float* x        = (const float*)d_in[0];
    const int*   pos_ids  = (const int*)d_in[1];
    const int*   tpos_ids = (const int*)d_in[2];
    const float* qkv_w    = (const float*)d_in[3];
    const float* qkv_b    = (const float*)d_in[4];
    const float* proj_w   = (const float*)d_in[5];
    const float* proj_b   = (const float*)d_in[6];
    const float* qn_w     = (const float*)d_in[7];
    const float* kn_w     = (const float*)d_in[8];
    const float* ln1_w    = (const float*)d_in[9];
    const float* ln2_w    = (const float*)d_in[10];
    const float* gate_w   = (const float*)d_in[11];
    const float* up_w     = (const float*)d_in[12];
    const float* down_w   = (const float*)d_in[13];
    float* out = (float*)d_out;
    float* ws  = (float*)d_ws;

    // workspace layout (floats)
    float* qkvb = ws;                      //  7,864,320  (M x 3072)
    float* Qb   = ws + 7864320;            //  2,621,440  (B*H, N, 64)
    float* Kb   = ws + 10485760;           //  2,621,440
    float* Vb   = ws + 13107200;           //  2,621,440
    float* hb   = ws + 15728640;           //  2,621,440  (M x C)
    float* yb   = ws + 18350080;           //  2,621,440  (xn / attn-o / y)
    float* tb   = ws;                      // 10,485,760  (M x I) aliases qkvb+Qb

    // 1. xn = RMS(x, ln1)
    rms_kernel<<<Mrows, 256, 0, stream>>>(x, ln1_w, yb);
    // 2. qkv = xn @ qkv_w[seg] + qkv_b[seg]
    gemm_seg<true, false><<<dim3(Mrows / 64, 3072 / 64), 256, 0, stream>>>(
        yb, qkv_w, qkv_b, nullptr, qkvb, Cc, 3 * Cc);
    // 3. split + q/k RMS + RoPE
    split_rope<<<Mrows, 256, 0, stream>>>(qkvb, qn_w, kn_w, pos_ids, tpos_ids,
                                          Qb, Kb, Vb);
    // 4. attention -> o (B,N,C) in yb
    attn_kernel<<<dim3(Nn / 64, Bb * Hh), 64, 0, stream>>>(Qb, Kb, Vb, yb);
    // 5. h = x + o @ proj_w[seg] + proj_b[seg]
    gemm_seg<true, true><<<dim3(Mrows / 64, Cc / 64), 256, 0, stream>>>(
        yb, proj_w, proj_b, x, hb, Cc, Cc);
    // 6. y = RMS(h, ln2)
    rms_kernel<<<Mrows, 256, 0, stream>>>(hb, ln2_w, yb);
    // 7. t = silu(y@gate) * (y@up)
    gemm_gateup<<<dim3(Mrows / 64, Ii / 64), 256, 0, stream>>>(yb, gate_w, up_w, tb);
    // 8. out = h + t @ down_w[seg]
    gemm_seg<false, true><<<dim3(Mrows / 64, Cc / 64), 256, 0, stream>>>(
        tb, down_w, nullptr, hb, out, Ii, Cc);
}

// Round 2
// 1710.632 us; speedup vs baseline: 3.8089x; 3.8089x over previous
//
#include <hip/hip_runtime.h>
#include <math.h>

// Problem constants (fixed by setup_inputs)
constexpr int Bb  = 2;
constexpr int Nn  = 1280;
constexpr int Cc  = 1024;
constexpr int Hh  = 16;
constexpr int DH  = 64;
constexpr int Ii  = 4096;
constexpr int Tt  = 256;    // text_len
constexpr int BSz = 128;    // block_size
constexpr int L1  = 4;      // len1
constexpr int Mrows = Bb * Nn;  // 2560

__device__ __forceinline__ int segof(int n) {
    return n < Tt ? 0 : (n < Tt + L1 * BSz ? 1 : 2);
}

// ---------------------------------------------------------------------------
// RMSNorm: one block per row, 256 threads, C=1024 (one float4 per thread)
// ---------------------------------------------------------------------------
__global__ __launch_bounds__(256)
void rms_kernel(const float* __restrict__ in, const float* __restrict__ w,
                float* __restrict__ out) {
    int row = blockIdx.x;                 // 0..M-1
    int n   = row % Nn;
    int seg = segof(n);
    const float* x = in + (size_t)row * Cc;
    int t = threadIdx.x;
    float4 xv = reinterpret_cast<const float4*>(x)[t];
    float ss = xv.x * xv.x + xv.y * xv.y + xv.z * xv.z + xv.w * xv.w;
#pragma unroll
    for (int off = 32; off; off >>= 1) ss += __shfl_down(ss, off, 64);
    __shared__ float red[4];
    __shared__ float s_r;
    int lane = t & 63, wid = t >> 6;
    if (lane == 0) red[wid] = ss;
    __syncthreads();
    if (t == 0) s_r = rsqrtf((red[0] + red[1] + red[2] + red[3]) * (1.0f / Cc) + 1e-6f);
    __syncthreads();
    float r = s_r;
    float4 wv = reinterpret_cast<const float4*>(w + (size_t)seg * Cc)[t];
    float4 ov;
    ov.x = wv.x * xv.x * r;
    ov.y = wv.y * xv.y * r;
    ov.z = wv.z * xv.z * r;
    ov.w = wv.w * xv.w * r;
    reinterpret_cast<float4*>(out + (size_t)row * Cc)[t] = ov;
}

// ---------------------------------------------------------------------------
// Generic segment-indexed fp32 GEMM: out[M x Nd] = A[M x K] @ W[seg][K x Nd]
// (+ bias[seg][Nd]) (+ res[M x Nd]).  64x64 tile, 256 thr, 4x4 microtile.
// ---------------------------------------------------------------------------
template <bool BIAS, bool RES>
__global__ __launch_bounds__(256)
void gemm_seg(const float* __restrict__ A, const float* __restrict__ W,
              const float* __restrict__ bias, const float* __restrict__ res,
              float* __restrict__ out, int K, int Nd) {
    int rb  = blockIdx.x * 64, cb = blockIdx.y * 64;
    int seg = segof(rb % Nn);
    const float* Wp = W + (size_t)seg * K * Nd;
    __shared__ float As[16][68];   // padded, 16B-aligned rows
    __shared__ float Bs2[16][64];
    int tid = threadIdx.x;
    int tx = tid & 15, ty = tid >> 4;
    float acc[4][4] = {};
    for (int kt = 0; kt < K; kt += 16) {
#pragma unroll
        for (int i = 0; i < 4; i++) {
            int idx = tid + i * 256;
            As[idx & 15][idx >> 4] =
                A[(size_t)(rb + (idx >> 4)) * K + kt + (idx & 15)];
        }
#pragma unroll
        for (int i = 0; i < 4; i++) {
            int idx = tid + i * 256;
            Bs2[idx >> 6][idx & 63] =
                Wp[(size_t)(kt + (idx >> 6)) * Nd + cb + (idx & 63)];
        }
        __syncthreads();
#pragma unroll
        for (int kk = 0; kk < 16; kk++) {
            float4 av = *reinterpret_cast<const float4*>(&As[kk][ty * 4]);
            float4 bv = *reinterpret_cast<const float4*>(&Bs2[kk][tx * 4]);
            acc[0][0] += av.x * bv.x; acc[0][1] += av.x * bv.y;
            acc[0][2] += av.x * bv.z; acc[0][3] += av.x * bv.w;
            acc[1][0] += av.y * bv.x; acc[1][1] += av.y * bv.y;
            acc[1][2] += av.y * bv.z; acc[1][3] += av.y * bv.w;
            acc[2][0] += av.z * bv.x; acc[2][1] += av.z * bv.y;
            acc[2][2] += av.z * bv.z; acc[2][3] += av.z * bv.w;
            acc[3][0] += av.w * bv.x; acc[3][1] += av.w * bv.y;
            acc[3][2] += av.w * bv.z; acc[3][3] += av.w * bv.w;
        }
        __syncthreads();
    }
#pragma unroll
    for (int i = 0; i < 4; i++) {
        int r = rb + ty * 4 + i;
        float4 v = make_float4(acc[i][0], acc[i][1], acc[i][2], acc[i][3]);
        if (BIAS) {
            float4 bv = *reinterpret_cast<const float4*>(bias + (size_t)seg * Nd + cb + tx * 4);
            v.x += bv.x; v.y += bv.y; v.z += bv.z; v.w += bv.w;
        }
        if (RES) {
            float4 rv = *reinterpret_cast<const float4*>(res + (size_t)r * Nd + cb + tx * 4);
            v.x += rv.x; v.y += rv.y; v.z += rv.z; v.w += rv.w;
        }
        *reinterpret_cast<float4*>(out + (size_t)r * Nd + cb + tx * 4) = v;
    }
}

// ---------------------------------------------------------------------------
// Fused gate/up GEMM + SiLU:  t = silu(y @ gate_w[seg]) * (y @ up_w[seg])
// ---------------------------------------------------------------------------
__global__ __launch_bounds__(256)
void gemm_gateup(const float* __restrict__ A, const float* __restrict__ G,
                 const float* __restrict__ U, float* __restrict__ out) {
    const int K = Cc, Nd = Ii;
    int rb  = blockIdx.x * 64, cb = blockIdx.y * 64;
    int seg = segof(rb % Nn);
    const float* Gp = G + (size_t)seg * K * Nd;
    const float* Up = U + (size_t)seg * K * Nd;
    __shared__ float As[16][68];
    __shared__ float Gs[16][64];
    __shared__ float Us[16][64];
    int tid = threadIdx.x;
    int tx = tid & 15, ty = tid >> 4;
    float accG[4][4] = {}, accU[4][4] = {};
    for (int kt = 0; kt < K; kt += 16) {
#pragma unroll
        for (int i = 0; i < 4; i++) {
            int idx = tid + i * 256;
            As[idx & 15][idx >> 4] =
                A[(size_t)(rb + (idx >> 4)) * K + kt + (idx & 15)];
        }
#pragma unroll
        for (int i = 0; i < 4; i++) {
            int idx = tid + i * 256;
            size_t woff = (size_t)(kt + (idx >> 6)) * Nd + cb + (idx & 63);
            Gs[idx >> 6][idx & 63] = Gp[woff];
            Us[idx >> 6][idx & 63] = Up[woff];
        }
        __syncthreads();
#pragma unroll
        for (int kk = 0; kk < 16; kk++) {
            float4 av = *reinterpret_cast<const float4*>(&As[kk][ty * 4]);
            float4 gv = *reinterpret_cast<const float4*>(&Gs[kk][tx * 4]);
            float4 uv = *reinterpret_cast<const float4*>(&Us[kk][tx * 4]);
            accG[0][0] += av.x * gv.x; accG[0][1] += av.x * gv.y;
            accG[0][2] += av.x * gv.z; accG[0][3] += av.x * gv.w;
            accG[1][0] += av.y * gv.x; accG[1][1] += av.y * gv.y;
            accG[1][2] += av.y * gv.z; accG[1][3] += av.y * gv.w;
            accG[2][0] += av.z * gv.x; accG[2][1] += av.z * gv.y;
            accG[2][2] += av.z * gv.z; accG[2][3] += av.z * gv.w;
            accG[3][0] += av.w * gv.x; accG[3][1] += av.w * gv.y;
            accG[3][2] += av.w * gv.z; accG[3][3] += av.w * gv.w;
            accU[0][0] += av.x * uv.x; accU[0][1] += av.x * uv.y;
            accU[0][2] += av.x * uv.z; accU[0][3] += av.x * uv.w;
            accU[1][0] += av.y * uv.x; accU[1][1] += av.y * uv.y;
            accU[1][2] += av.y * uv.z; accU[1][3] += av.y * uv.w;
            accU[2][0] += av.z * uv.x; accU[2][1] += av.z * uv.y;
            accU[2][2] += av.z * uv.z; accU[2][3] += av.z * uv.w;
            accU[3][0] += av.w * uv.x; accU[3][1] += av.w * uv.y;
            accU[3][2] += av.w * uv.z; accU[3][3] += av.w * uv.w;
        }
        __syncthreads();
    }
#pragma unroll
    for (int i = 0; i < 4; i++) {
        int r = rb + ty * 4 + i;
        float4 v;
        float g0 = accG[i][0], g1 = accG[i][1], g2 = accG[i][2], g3 = accG[i][3];
        v.x = g0 / (1.f + expf(-g0)) * accU[i][0];
        v.y = g1 / (1.f + expf(-g1)) * accU[i][1];
        v.z = g2 / (1.f + expf(-g2)) * accU[i][2];
        v.w = g3 / (1.f + expf(-g3)) * accU[i][3];
        *reinterpret_cast<float4*>(out + (size_t)r * Ii + cb + tx * 4) = v;
    }
}

// ---------------------------------------------------------------------------
// Split qkv + per-head q/k RMSNorm + RoPE.
// ---------------------------------------------------------------------------
__global__ __launch_bounds__(256)
void split_rope(const float* __restrict__ qkv, const float* __restrict__ qn_w,
                const float* __restrict__ kn_w, const int* __restrict__ pos_ids,
                const int* __restrict__ tpos_ids, float* __restrict__ Q,
                float* __restrict__ K, float* __restrict__ V) {
    int row = blockIdx.x;   // b*N + n
    int b = row / Nn, n = row % Nn;
    int seg = segof(n);
    int lane = threadIdx.x & 63, wid = threadIdx.x >> 6;
    int pos = (n < Tt) ? tpos_ids[n] : pos_ids[n - Tt];
    int j = lane & 31;
    float ang = (float)pos * exp2f(-(float)j * (13.287712379549449f / 32.f));
    float cv = cosf(ang), sv = sinf(ang);
    float qw = qn_w[seg * DH + lane], kw = kn_w[seg * DH + lane];
    for (int h = wid; h < Hh; h += 4) {
        const float* base = qkv + (size_t)row * (3 * Cc) + h * DH + lane;
        float q = base[0], k = base[Cc], v = base[2 * Cc];
        float qs = q * q, ks = k * k;
#pragma unroll
        for (int off = 32; off; off >>= 1) {
            qs += __shfl_xor(qs, off, 64);
            ks += __shfl_xor(ks, off, 64);
        }
        q = q * rsqrtf(qs * (1.f / DH) + 1e-6f) * qw;
        k = k * rsqrtf(ks * (1.f / DH) + 1e-6f) * kw;
        float qp = __shfl_xor(q, 32, 64);
        float kp = __shfl_xor(k, 32, 64);
        float qo = q * cv + ((lane < 32) ? -qp * sv : qp * sv);
        float ko = k * cv + ((lane < 32) ? -kp * sv : kp * sv);
        size_t oidx = ((size_t)(b * Hh + h) * Nn + n) * DH + lane;
        Q[oidx] = qo;
        K[oidx] = ko;
        V[oidx] = v;
    }
}

// ---------------------------------------------------------------------------
// Flash-style attention, v2: 4 waves per block, split-K with per-wave private
// LDS K/V tiles (no main-loop barriers), tile-level mask skipping, LDS
// combine of per-wave partials (o-buffer aliases K/V buffers, XOR-swizzled).
// Grid (N/64, B*H), 256 threads. Lane = q-row.
// ---------------------------------------------------------------------------
__global__ __launch_bounds__(256)
void attn_kernel(const float* __restrict__ Qg, const float* __restrict__ Kg,
                 const float* __restrict__ Vg, float* __restrict__ O) {
    constexpr int KT = 32;   // k rows per wave tile
    constexpr int NW = 4;    // waves per block
    int qt = blockIdx.x;
    int bh = blockIdx.y;
    int b = bh >> 4, h = bh & 15;
    int tid = threadIdx.x;
    int lane = tid & 63, wid = tid >> 6;

    __shared__ float smem[NW * 2 * KT * 64];   // 64 KB: per-wave K/V; later o-combine
    __shared__ float mbuf[NW][64], lbuf[NW][64];
    float* kbuf = &smem[(wid * 2 + 0) * KT * 64];
    float* vbuf = &smem[(wid * 2 + 1) * KT * 64];

    const size_t headoff = (size_t)bh * Nn * DH;
    int q0 = qt * 64;
    int qi = q0 + lane;
    float qreg[64];
#pragma unroll
    for (int d4 = 0; d4 < 16; d4++) {
        float4 t4 = *reinterpret_cast<const float4*>(&Qg[headoff + (size_t)qi * DH + d4 * 4]);
        qreg[4 * d4 + 0] = t4.x; qreg[4 * d4 + 1] = t4.y;
        qreg[4 * d4 + 2] = t4.z; qreg[4 * d4 + 3] = t4.w;
    }
    bool qtext = q0 < Tt;            // whole 64-row q-tile shares category
    int qb = qtext ? 0 : (q0 - Tt) / BSz;

    float m = -3.4e38f, l = 0.f;
    float o[64];
#pragma unroll
    for (int d = 0; d < 64; d++) o[d] = 0.f;

    for (int kt = wid; kt < Nn / KT; kt += NW) {
        int kbase = kt * KT;
        // tile-level visibility (uniform across the wave)
        bool vis;
        if (qtext) {
            vis = (kbase <= q0 + 63);              // causal text-only
        } else if (kbase < Tt) {
            vis = true;                            // image q sees all text
        } else {
            int kb = (kbase - Tt) / BSz;           // k-tile inside one 128-block
            vis = (qb < L1) ? (kb <= qb)
                            : ((kb < L1 && qb - L1 > kb) || kb == qb);
        }
        if (!vis) continue;
        // stage K,V tile (private per wave -> no barrier needed)
#pragma unroll
        for (int p = 0; p < 8; p++) {
            int e = p * 64 + lane;
            int r = e >> 4, c = (e & 15) * 4;
            *reinterpret_cast<float4*>(&kbuf[r * 64 + c]) =
                *reinterpret_cast<const float4*>(&Kg[headoff + (size_t)(kbase + r) * DH + c]);
            *reinterpret_cast<float4*>(&vbuf[r * 64 + c]) =
                *reinterpret_cast<const float4*>(&Vg[headoff + (size_t)(kbase + r) * DH + c]);
        }
        for (int kc = 0; kc < KT / 16; kc++) {
            float s[16];
#pragma unroll
            for (int kk = 0; kk < 16; kk++) {
                int kr = kc * 16 + kk;
                float4 a = make_float4(0.f, 0.f, 0.f, 0.f);
#pragma unroll
                for (int d4 = 0; d4 < 16; d4++) {
                    float4 kv4 = *reinterpret_cast<const float4*>(&kbuf[kr * 64 + d4 * 4]);
                    a.x += qreg[4 * d4 + 0] * kv4.x;
                    a.y += qreg[4 * d4 + 1] * kv4.y;
                    a.z += qreg[4 * d4 + 2] * kv4.z;
                    a.w += qreg[4 * d4 + 3] * kv4.w;
                }
                float acc = (a.x + a.y) + (a.z + a.w);
                int ki = kbase + kr;
                bool ok = !qtext || (qi >= ki);    // only text diag is partial
                s[kk] = ok ? acc * 0.125f : -3.4e38f;
            }
            float tmax = s[0];
#pragma unroll
            for (int kk = 1; kk < 16; kk++) tmax = fmaxf(tmax, s[kk]);
            if (tmax > -1e38f) {
                float mnew = fmaxf(m, tmax);
                float sc = __expf(m - mnew);
                l *= sc;
#pragma unroll
                for (int d = 0; d < 64; d++) o[d] *= sc;
#pragma unroll
                for (int kk = 0; kk < 16; kk++) {
                    float p = __expf(s[kk] - mnew);
                    l += p;
#pragma unroll
                    for (int d4 = 0; d4 < 16; d4++) {
                        float4 vv = *reinterpret_cast<const float4*>(&vbuf[(kc * 16 + kk) * 64 + d4 * 4]);
                        o[4 * d4 + 0] += p * vv.x;
                        o[4 * d4 + 1] += p * vv.y;
                        o[4 * d4 + 2] += p * vv.z;
                        o[4 * d4 + 3] += p * vv.w;
                    }
                }
                m = mnew;
            }
        }
    }

    // ---- combine per-wave partials ----
    __syncthreads();                 // everyone done with K/V LDS
    mbuf[wid][lane] = m;
    lbuf[wid][lane] = l;
    int sw = (lane & 15) << 2;       // XOR swizzle to spread banks
#pragma unroll
    for (int d4 = 0; d4 < 16; d4++) {
        int d = d4 * 4, dd = d ^ sw;
        *reinterpret_cast<float4*>(&smem[(wid * 64 + lane) * 64 + dd]) =
            make_float4(o[d], o[d + 1], o[d + 2], o[d + 3]);
    }
    __syncthreads();
    float mm0 = mbuf[0][lane], mm1 = mbuf[1][lane];
    float mm2 = mbuf[2][lane], mm3 = mbuf[3][lane];
    float mstar = fmaxf(fmaxf(mm0, mm1), fmaxf(mm2, mm3));
    float c0 = __expf(mm0 - mstar), c1 = __expf(mm1 - mstar);
    float c2 = __expf(mm2 - mstar), c3 = __expf(mm3 - mstar);
    float lstar = c0 * lbuf[0][lane] + c1 * lbuf[1][lane] +
                  c2 * lbuf[2][lane] + c3 * lbuf[3][lane];
    float inv = 1.f / lstar;
#pragma unroll
    for (int d4 = 0; d4 < 4; d4++) {
        int d = wid * 16 + d4 * 4, dd = d ^ sw;
        float4 a0 = *reinterpret_cast<float4*>(&smem[(0 * 64 + lane) * 64 + dd]);
        float4 a1 = *reinterpret_cast<float4*>(&smem[(1 * 64 + lane) * 64 + dd]);
        float4 a2 = *reinterpret_cast<float4*>(&smem[(2 * 64 + lane) * 64 + dd]);
        float4 a3 = *reinterpret_cast<float4*>(&smem[(3 * 64 + lane) * 64 + dd]);
        float4 r;
        r.x = (c0 * a0.x + c1 * a1.x + c2 * a2.x + c3 * a3.x) * inv;
        r.y = (c0 * a0.y + c1 * a1.y + c2 * a2.y + c3 * a3.y) * inv;
        r.z = (c0 * a0.z + c1 * a1.z + c2 * a2.z + c3 * a3.z) * inv;
        r.w = (c0 * a0.w + c1 * a1.w + c2 * a2.w + c3 * a3.w) * inv;
        *reinterpret_cast<float4*>(&O[((size_t)b * Nn + qi) * Cc + h * DH + d]) = r;
    }
}

// ---------------------------------------------------------------------------
// kernel_launch
// ---------------------------------------------------------------------------
extern "C" void kernel_launch(void* const* d_in, const int* in_sizes, int n_in,
                              void* d_out, int out_size, void* d_ws, size_t ws_size,
                              hipStream_t stream) {
    const float* x        = (const float*)d_in[0];
    const int*   pos_ids  = (const int*)d_in[1];
    const int*   tpos_ids = (const int*)d_in[2];
    const float* qkv_w    = (const float*)d_in[3];
    const float* qkv_b    = (const float*)d_in[4];
    const float* proj_w   = (const float*)d_in[5];
    const float* proj_b   = (const float*)d_in[6];
    const float* qn_w     = (const float*)d_in[7];
    const float* kn_w     = (const float*)d_in[8];
    const float* ln1_w    = (const float*)d_in[9];
    const float* ln2_w    = (const float*)d_in[10];
    const float* gate_w   = (const float*)d_in[11];
    const float* up_w     = (const float*)d_in[12];
    const float* down_w   = (const float*)d_in[13];
    float* out = (float*)d_out;
    float* ws  = (float*)d_ws;

    // workspace layout (floats)
    float* qkvb = ws;                      //  7,864,320  (M x 3072)
    float* Qb   = ws + 7864320;            //  2,621,440  (B*H, N, 64)
    float* Kb   = ws + 10485760;           //  2,621,440
    float* Vb   = ws + 13107200;           //  2,621,440
    float* hb   = ws + 15728640;           //  2,621,440  (M x C)
    float* yb   = ws + 18350080;           //  2,621,440  (xn / attn-o / y)
    float* tb   = ws;                      // 10,485,760  (M x I) aliases qkvb+Qb

    // 1. xn = RMS(x, ln1)
    rms_kernel<<<Mrows, 256, 0, stream>>>(x, ln1_w, yb);
    // 2. qkv = xn @ qkv_w[seg] + qkv_b[seg]
    gemm_seg<true, false><<<dim3(Mrows / 64, 3072 / 64), 256, 0, stream>>>(
        yb, qkv_w, qkv_b, nullptr, qkvb, Cc, 3 * Cc);
    // 3. split + q/k RMS + RoPE
    split_rope<<<Mrows, 256, 0, stream>>>(qkvb, qn_w, kn_w, pos_ids, tpos_ids,
                                          Qb, Kb, Vb);
    // 4. attention -> o (B,N,C) in yb
    attn_kernel<<<dim3(Nn / 64, Bb * Hh), 256, 0, stream>>>(Qb, Kb, Vb, yb);
    // 5. h = x + o @ proj_w[seg] + proj_b[seg]
    gemm_seg<true, true><<<dim3(Mrows / 64, Cc / 64), 256, 0, stream>>>(
        yb, proj_w, proj_b, x, hb, Cc, Cc);
    // 6. y = RMS(h, ln2)
    rms_kernel<<<Mrows, 256, 0, stream>>>(hb, ln2_w, yb);
    // 7. t = silu(y@gate) * (y@up)
    gemm_gateup<<<dim3(Mrows / 64, Ii / 64), 256, 0, stream>>>(yb, gate_w, up_w, tb);
    // 8. out = h + t @ down_w[seg]
    gemm_seg<false, true><<<dim3(Mrows / 64, Cc / 64), 256, 0, stream>>>(
        tb, down_w, nullptr, hb, out, Ii, Cc);
}

// Round 4
// 588.233 us; speedup vs baseline: 11.0765x; 2.9081x over previous
//
#include <hip/hip_runtime.h>
#include <math.h>

// Problem constants (fixed by setup_inputs)
constexpr int Bb  = 2;
constexpr int Nn  = 1280;
constexpr int Cc  = 1024;
constexpr int Hh  = 16;
constexpr int DH  = 64;
constexpr int Ii  = 4096;
constexpr int Tt  = 256;    // text_len
constexpr int BSz = 128;    // block_size
constexpr int L1  = 4;      // len1
constexpr int Mrows = Bb * Nn;  // 2560

typedef __attribute__((ext_vector_type(8))) short short8v;
typedef __attribute__((ext_vector_type(4))) float f32x4;

__device__ __forceinline__ int segof(int n) {
    return n < Tt ? 0 : (n < Tt + L1 * BSz ? 1 : 2);
}
__device__ __forceinline__ unsigned short f2bf(float f) {
    unsigned int u = __float_as_uint(f);
    u += 0x7fffu + ((u >> 16) & 1u);        // RNE
    return (unsigned short)(u >> 16);
}
__device__ __forceinline__ float bf2f(unsigned short h) {
    return __uint_as_float(((unsigned int)h) << 16);
}

// ---------------------------------------------------------------------------
// RMSNorm fp32 -> bf16 out: one block per row, 256 threads, C=1024
// ---------------------------------------------------------------------------
__global__ __launch_bounds__(256)
void rms_bf16(const float* __restrict__ in, const float* __restrict__ w,
              unsigned short* __restrict__ out) {
    int row = blockIdx.x;
    int n   = row % Nn;
    int seg = segof(n);
    const float* x = in + (size_t)row * Cc;
    int t = threadIdx.x;
    float4 xv = reinterpret_cast<const float4*>(x)[t];
    float ss = xv.x * xv.x + xv.y * xv.y + xv.z * xv.z + xv.w * xv.w;
#pragma unroll
    for (int off = 32; off; off >>= 1) ss += __shfl_down(ss, off, 64);
    __shared__ float red[4];
    __shared__ float s_r;
    int lane = t & 63, wid = t >> 6;
    if (lane == 0) red[wid] = ss;
    __syncthreads();
    if (t == 0) s_r = rsqrtf((red[0] + red[1] + red[2] + red[3]) * (1.0f / Cc) + 1e-6f);
    __syncthreads();
    float r = s_r;
    float4 wv = reinterpret_cast<const float4*>(w + (size_t)seg * Cc)[t];
    ushort4 ov;
    ov.x = f2bf(wv.x * xv.x * r);
    ov.y = f2bf(wv.y * xv.y * r);
    ov.z = f2bf(wv.z * xv.z * r);
    ov.w = f2bf(wv.w * xv.w * r);
    *reinterpret_cast<ushort4*>(&out[(size_t)row * Cc + t * 4]) = ov;
}

// ---------------------------------------------------------------------------
// Pack fp32 weights [3][K][Nd] into fragment-linear bf16 layout:
// PB[seg][kt][cb][fr(8)][lane(64)] of 8 bf16, where element (j=0..7) =
//   W[seg][kt*32 + (lane>>4)*8 + j][cb*128 + fr*16 + (lane&15)]
// ---------------------------------------------------------------------------
__global__ __launch_bounds__(256)
void pack_w(const float* __restrict__ W, unsigned short* __restrict__ PB,
            int K, int Nd) {
    size_t idx = (size_t)blockIdx.x * 256 + threadIdx.x;   // chunk id
    size_t cpseg = (size_t)K * Nd / 8;
    int s = (int)(idx / cpseg);
    size_t rm = idx % cpseg;
    int lane = (int)(rm & 63);
    int fr   = (int)((rm >> 6) & 7);
    size_t tile = rm >> 9;                  // kt*(Nd/128)+cb
    int nct = Nd >> 7;
    int cb = (int)(tile % nct);
    int kt = (int)(tile / nct);
    int col = cb * 128 + fr * 16 + (lane & 15);
    int k0  = kt * 32 + (lane >> 4) * 8;
    const float* src = W + ((size_t)s * K + k0) * Nd + col;
    unsigned short o[8];
#pragma unroll
    for (int j = 0; j < 8; j++) o[j] = f2bf(src[(size_t)j * Nd]);
    short8v v;
#pragma unroll
    for (int j = 0; j < 8; j++) v[j] = (short)o[j];
    *reinterpret_cast<short8v*>(&PB[idx * 8]) = v;
}

// ---------------------------------------------------------------------------
// bf16 MFMA GEMM: out[M x Nd] = A[M x K](bf16) @ PB[seg] (packed bf16)
// 128x128 tile, 256 thr (4 waves 2x2), BK=32, 16x16x32 MFMA.
// OUTMODE: 0 = f32 out, 1 = bf16 out, 2 = bf16 out with silu(acc)*U epilogue
// ---------------------------------------------------------------------------
template <int OUTMODE, bool BIAS, bool RES>
__global__ __launch_bounds__(256)
void gemm_mfma(const unsigned short* __restrict__ A,
               const unsigned short* __restrict__ PB,
               const float* __restrict__ bias, const float* __restrict__ res,
               const unsigned short* __restrict__ U, void* __restrict__ outp,
               int K, int Nd) {
    __shared__ __align__(16) unsigned short lds[8192];  // A frags, B frags
    int rb = blockIdx.x * 128, cb = blockIdx.y;
    int seg = segof(rb % Nn);
    int tid = threadIdx.x, lane = tid & 63, wid = tid >> 6;
    int wr = wid >> 1, wc = wid & 1;
    const unsigned short* PBseg = PB + (size_t)seg * K * Nd;
    const int nKt = K >> 5, nct = Nd >> 7;

    f32x4 acc[4][4];
#pragma unroll
    for (int i = 0; i < 4; i++)
#pragma unroll
        for (int j = 0; j < 4; j++) acc[i][j] = (f32x4){0.f, 0.f, 0.f, 0.f};

    for (int kt = 0; kt < nKt; ++kt) {
        short8v av[2], bv[2];
#pragma unroll
        for (int i = 0; i < 2; i++) {
            int c = tid + i * 256;          // chunk 0..511
            int mf = c >> 6, lc = c & 63;
            int row = rb + mf * 16 + (lc & 15);
            int k0  = kt * 32 + (lc >> 4) * 8;
            av[i] = *reinterpret_cast<const short8v*>(&A[(size_t)row * K + k0]);
            bv[i] = *reinterpret_cast<const short8v*>(
                &PBseg[((((size_t)kt * nct + cb) * 8 + mf) * 64 + lc) * 8]);
        }
        __syncthreads();                    // prev iteration's reads done
#pragma unroll
        for (int i = 0; i < 2; i++) {
            int c = tid + i * 256;
            *reinterpret_cast<short8v*>(&lds[(size_t)c * 8]) = av[i];
            *reinterpret_cast<short8v*>(&lds[4096 + (size_t)c * 8]) = bv[i];
        }
        __syncthreads();
        short8v afr[4], bfr[4];
#pragma unroll
        for (int m = 0; m < 4; m++)
            afr[m] = *reinterpret_cast<short8v*>(&lds[((wr * 4 + m) * 64 + lane) * 8]);
#pragma unroll
        for (int n = 0; n < 4; n++)
            bfr[n] = *reinterpret_cast<short8v*>(&lds[4096 + ((wc * 4 + n) * 64 + lane) * 8]);
#pragma unroll
        for (int m = 0; m < 4; m++)
#pragma unroll
            for (int n = 0; n < 4; n++)
                acc[m][n] = __builtin_amdgcn_mfma_f32_16x16x32_bf16(
                    afr[m], bfr[n], acc[m][n], 0, 0, 0);
    }

    // epilogue: C/D layout col=lane&15, row=(lane>>4)*4+r
    float* outf = (float*)outp;
    unsigned short* outh = (unsigned short*)outp;
#pragma unroll
    for (int n = 0; n < 4; n++) {
        int col = cb * 128 + wc * 64 + n * 16 + (lane & 15);
        float bvv = BIAS ? bias[(size_t)seg * Nd + col] : 0.f;
#pragma unroll
        for (int m = 0; m < 4; m++) {
#pragma unroll
            for (int r = 0; r < 4; r++) {
                int row = rb + wr * 64 + m * 16 + (lane >> 4) * 4 + r;
                float v = acc[m][n][r] + bvv;
                if (RES) v += res[(size_t)row * Nd + col];
                if (OUTMODE == 0) {
                    outf[(size_t)row * Nd + col] = v;
                } else if (OUTMODE == 1) {
                    outh[(size_t)row * Nd + col] = f2bf(v);
                } else {
                    float u = bf2f(U[(size_t)row * Nd + col]);
                    float t = v / (1.f + __expf(-v)) * u;
                    outh[(size_t)row * Nd + col] = f2bf(t);
                }
            }
        }
    }
}

// ---------------------------------------------------------------------------
// Split qkv(bf16) + per-head q/k RMSNorm + RoPE -> bf16 Q,K,V (bh, n, dh)
// ---------------------------------------------------------------------------
__global__ __launch_bounds__(256)
void split_rope(const unsigned short* __restrict__ qkv,
                const float* __restrict__ qn_w, const float* __restrict__ kn_w,
                const int* __restrict__ pos_ids, const int* __restrict__ tpos_ids,
                unsigned short* __restrict__ Q, unsigned short* __restrict__ K,
                unsigned short* __restrict__ V) {
    int row = blockIdx.x;   // b*N + n
    int b = row / Nn, n = row % Nn;
    int seg = segof(n);
    int lane = threadIdx.x & 63, wid = threadIdx.x >> 6;
    int pos = (n < Tt) ? tpos_ids[n] : pos_ids[n - Tt];
    int j = lane & 31;
    float ang = (float)pos * exp2f(-(float)j * (13.287712379549449f / 32.f));
    float cv = cosf(ang), sv = sinf(ang);
    float qw = qn_w[seg * DH + lane], kw = kn_w[seg * DH + lane];
    for (int h = wid; h < Hh; h += 4) {
        const unsigned short* base = qkv + (size_t)row * (3 * Cc) + h * DH + lane;
        float q = bf2f(base[0]), k = bf2f(base[Cc]), v = bf2f(base[2 * Cc]);
        float qs = q * q, ks = k * k;
#pragma unroll
        for (int off = 32; off; off >>= 1) {
            qs += __shfl_xor(qs, off, 64);
            ks += __shfl_xor(ks, off, 64);
        }
        q = q * rsqrtf(qs * (1.f / DH) + 1e-6f) * qw;
        k = k * rsqrtf(ks * (1.f / DH) + 1e-6f) * kw;
        float qp = __shfl_xor(q, 32, 64);
        float kp = __shfl_xor(k, 32, 64);
        float qo = q * cv + ((lane < 32) ? -qp * sv : qp * sv);
        float ko = k * cv + ((lane < 32) ? -kp * sv : kp * sv);
        size_t oidx = ((size_t)(b * Hh + h) * Nn + n) * DH + lane;
        Q[oidx] = f2bf(qo);
        K[oidx] = f2bf(ko);
        V[oidx] = f2bf(v);
    }
}

// ---------------------------------------------------------------------------
// Flash-style attention (bf16 in, bf16 out), 4 waves split-K, private LDS
// K/V fp32 tiles, tile-level mask skipping, LDS combine.
// ---------------------------------------------------------------------------
__global__ __launch_bounds__(256)
void attn_kernel(const unsigned short* __restrict__ Qg,
                 const unsigned short* __restrict__ Kg,
                 const unsigned short* __restrict__ Vg,
                 unsigned short* __restrict__ O) {
    constexpr int KT = 32;
    constexpr int NW = 4;
    int qt = blockIdx.x;
    int bh = blockIdx.y;
    int b = bh >> 4, h = bh & 15;
    int tid = threadIdx.x;
    int lane = tid & 63, wid = tid >> 6;

    __shared__ float smem[NW * 2 * KT * 64];
    __shared__ float mbuf[NW][64], lbuf[NW][64];
    float* kbuf = &smem[(wid * 2 + 0) * KT * 64];
    float* vbuf = &smem[(wid * 2 + 1) * KT * 64];

    const size_t headoff = (size_t)bh * Nn * DH;
    int q0 = qt * 64;
    int qi = q0 + lane;
    float qreg[64];
#pragma unroll
    for (int d8 = 0; d8 < 8; d8++) {
        ushort4 t4a = *reinterpret_cast<const ushort4*>(&Qg[headoff + (size_t)qi * DH + d8 * 8]);
        ushort4 t4b = *reinterpret_cast<const ushort4*>(&Qg[headoff + (size_t)qi * DH + d8 * 8 + 4]);
        qreg[8 * d8 + 0] = bf2f(t4a.x); qreg[8 * d8 + 1] = bf2f(t4a.y);
        qreg[8 * d8 + 2] = bf2f(t4a.z); qreg[8 * d8 + 3] = bf2f(t4a.w);
        qreg[8 * d8 + 4] = bf2f(t4b.x); qreg[8 * d8 + 5] = bf2f(t4b.y);
        qreg[8 * d8 + 6] = bf2f(t4b.z); qreg[8 * d8 + 7] = bf2f(t4b.w);
    }
    bool qtext = q0 < Tt;
    int qb = qtext ? 0 : (q0 - Tt) / BSz;

    float m = -3.4e38f, l = 0.f;
    float o[64];
#pragma unroll
    for (int d = 0; d < 64; d++) o[d] = 0.f;

    for (int kt = wid; kt < Nn / KT; kt += NW) {
        int kbase = kt * KT;
        bool vis;
        if (qtext) {
            vis = (kbase <= q0 + 63);
        } else if (kbase < Tt) {
            vis = true;
        } else {
            int kb = (kbase - Tt) / BSz;
            vis = (qb < L1) ? (kb <= qb)
                            : ((kb < L1 && qb - L1 > kb) || kb == qb);
        }
        if (!vis) continue;
        // stage 32 rows x 64 cols: 256 chunks of 8 bf16 (4 per lane)
#pragma unroll
        for (int p = 0; p < 4; p++) {
            int e = p * 64 + lane;          // 0..255
            int r = e >> 3, c = (e & 7) * 8;
            const unsigned short* ksrc = &Kg[headoff + (size_t)(kbase + r) * DH + c];
            const unsigned short* vsrc = &Vg[headoff + (size_t)(kbase + r) * DH + c];
            ushort4 ka = *reinterpret_cast<const ushort4*>(ksrc);
            ushort4 kb4 = *reinterpret_cast<const ushort4*>(ksrc + 4);
            ushort4 va = *reinterpret_cast<const ushort4*>(vsrc);
            ushort4 vb4 = *reinterpret_cast<const ushort4*>(vsrc + 4);
            *reinterpret_cast<float4*>(&kbuf[r * 64 + c]) =
                make_float4(bf2f(ka.x), bf2f(ka.y), bf2f(ka.z), bf2f(ka.w));
            *reinterpret_cast<float4*>(&kbuf[r * 64 + c + 4]) =
                make_float4(bf2f(kb4.x), bf2f(kb4.y), bf2f(kb4.z), bf2f(kb4.w));
            *reinterpret_cast<float4*>(&vbuf[r * 64 + c]) =
                make_float4(bf2f(va.x), bf2f(va.y), bf2f(va.z), bf2f(va.w));
            *reinterpret_cast<float4*>(&vbuf[r * 64 + c + 4]) =
                make_float4(bf2f(vb4.x), bf2f(vb4.y), bf2f(vb4.z), bf2f(vb4.w));
        }
        for (int kc = 0; kc < KT / 16; kc++) {
            float s[16];
#pragma unroll
            for (int kk = 0; kk < 16; kk++) {
                int kr = kc * 16 + kk;
                float4 a = make_float4(0.f, 0.f, 0.f, 0.f);
#pragma unroll
                for (int d4 = 0; d4 < 16; d4++) {
                    float4 kv4 = *reinterpret_cast<const float4*>(&kbuf[kr * 64 + d4 * 4]);
                    a.x += qreg[4 * d4 + 0] * kv4.x;
                    a.y += qreg[4 * d4 + 1] * kv4.y;
                    a.z += qreg[4 * d4 + 2] * kv4.z;
                    a.w += qreg[4 * d4 + 3] * kv4.w;
                }
                float acc = (a.x + a.y) + (a.z + a.w);
                int ki = kbase + kr;
                bool ok = !qtext || (qi >= ki);
                s[kk] = ok ? acc * 0.125f : -3.4e38f;
            }
            float tmax = s[0];
#pragma unroll
            for (int kk = 1; kk < 16; kk++) tmax = fmaxf(tmax, s[kk]);
            if (tmax > -1e38f) {
                float mnew = fmaxf(m, tmax);
                float sc = __expf(m - mnew);
                l *= sc;
#pragma unroll
                for (int d = 0; d < 64; d++) o[d] *= sc;
#pragma unroll
                for (int kk = 0; kk < 16; kk++) {
                    float p = __expf(s[kk] - mnew);
                    l += p;
#pragma unroll
                    for (int d4 = 0; d4 < 16; d4++) {
                        float4 vv = *reinterpret_cast<const float4*>(&vbuf[(kc * 16 + kk) * 64 + d4 * 4]);
                        o[4 * d4 + 0] += p * vv.x;
                        o[4 * d4 + 1] += p * vv.y;
                        o[4 * d4 + 2] += p * vv.z;
                        o[4 * d4 + 3] += p * vv.w;
                    }
                }
                m = mnew;
            }
        }
    }

    __syncthreads();
    mbuf[wid][lane] = m;
    lbuf[wid][lane] = l;
    int sw = (lane & 15) << 2;
#pragma unroll
    for (int d4 = 0; d4 < 16; d4++) {
        int d = d4 * 4, dd = d ^ sw;
        *reinterpret_cast<float4*>(&smem[(wid * 64 + lane) * 64 + dd]) =
            make_float4(o[d], o[d + 1], o[d + 2], o[d + 3]);
    }
    __syncthreads();
    float mm0 = mbuf[0][lane], mm1 = mbuf[1][lane];
    float mm2 = mbuf[2][lane], mm3 = mbuf[3][lane];
    float mstar = fmaxf(fmaxf(mm0, mm1), fmaxf(mm2, mm3));
    float c0 = __expf(mm0 - mstar), c1 = __expf(mm1 - mstar);
    float c2 = __expf(mm2 - mstar), c3 = __expf(mm3 - mstar);
    float lstar = c0 * lbuf[0][lane] + c1 * lbuf[1][lane] +
                  c2 * lbuf[2][lane] + c3 * lbuf[3][lane];
    float inv = 1.f / lstar;
#pragma unroll
    for (int d4 = 0; d4 < 4; d4++) {
        int d = wid * 16 + d4 * 4, dd = d ^ sw;
        float4 a0 = *reinterpret_cast<float4*>(&smem[(0 * 64 + lane) * 64 + dd]);
        float4 a1 = *reinterpret_cast<float4*>(&smem[(1 * 64 + lane) * 64 + dd]);
        float4 a2 = *reinterpret_cast<float4*>(&smem[(2 * 64 + lane) * 64 + dd]);
        float4 a3 = *reinterpret_cast<float4*>(&smem[(3 * 64 + lane) * 64 + dd]);
        ushort4 r;
        r.x = f2bf((c0 * a0.x + c1 * a1.x + c2 * a2.x + c3 * a3.x) * inv);
        r.y = f2bf((c0 * a0.y + c1 * a1.y + c2 * a2.y + c3 * a3.y) * inv);
        r.z = f2bf((c0 * a0.z + c1 * a1.z + c2 * a2.z + c3 * a3.z) * inv);
        r.w = f2bf((c0 * a0.w + c1 * a1.w + c2 * a2.w + c3 * a3.w) * inv);
        *reinterpret_cast<ushort4*>(&O[((size_t)b * Nn + qi) * Cc + h * DH + d]) = r;
    }
}

// ---------------------------------------------------------------------------
// kernel_launch
// ---------------------------------------------------------------------------
extern "C" void kernel_launch(void* const* d_in, const int* in_sizes, int n_in,
                              void* d_out, int out_size, void* d_ws, size_t ws_size,
                              hipStream_t stream) {
    const float* x        = (const float*)d_in[0];
    const int*   pos_ids  = (const int*)d_in[1];
    const int*   tpos_ids = (const int*)d_in[2];
    const float* qkv_w    = (const float*)d_in[3];
    const float* qkv_b    = (const float*)d_in[4];
    const float* proj_w   = (const float*)d_in[5];
    const float* proj_b   = (const float*)d_in[6];
    const float* qn_w     = (const float*)d_in[7];
    const float* kn_w     = (const float*)d_in[8];
    const float* ln1_w    = (const float*)d_in[9];
    const float* ln2_w    = (const float*)d_in[10];
    const float* gate_w   = (const float*)d_in[11];
    const float* up_w     = (const float*)d_in[12];
    const float* down_w   = (const float*)d_in[13];
    float* out = (float*)d_out;
    char*  wsb = (char*)d_ws;

    // workspace regions (bytes)
    unsigned short* Wp   = (unsigned short*)(wsb);              // 25,165,824 packed weights
    unsigned short* P1   = (unsigned short*)(wsb + 25165824);   // qkvbf / tbf (20.97 MB)
    unsigned short* P2   = (unsigned short*)(wsb + 46137344);   // Q,K,V bf16 / ubf (20.97 MB)
    unsigned short* P3   = (unsigned short*)(wsb + 67108864);   // xnbf/obf/ybf (5.24 MB)
    float*          hb   = (float*)(wsb + 72351744);            // 10.49 MB fp32
    unsigned short* Qbf  = P2;
    unsigned short* Kbf  = P2 + 2621440;
    unsigned short* Vbf  = P2 + 5242880;

    // 1. xn = RMS(x, ln1) -> bf16
    rms_bf16<<<Mrows, 256, 0, stream>>>(x, ln1_w, P3);
    // 2. pack qkv weights; qkv GEMM -> bf16
    pack_w<<<4608, 256, 0, stream>>>(qkv_w, Wp, Cc, 3 * Cc);
    gemm_mfma<1, true, false><<<dim3(Mrows / 128, 24), 256, 0, stream>>>(
        P3, Wp, qkv_b, nullptr, nullptr, P1, Cc, 3 * Cc);
    // 3. split + q/k RMS + RoPE (bf16)
    split_rope<<<Mrows, 256, 0, stream>>>(P1, qn_w, kn_w, pos_ids, tpos_ids,
                                          Qbf, Kbf, Vbf);
    // 4. attention -> obf (bf16, (B,N,C))
    attn_kernel<<<dim3(Nn / 64, Bb * Hh), 256, 0, stream>>>(Qbf, Kbf, Vbf, P3);
    // 5. h = x + o @ proj_w + proj_b  (fp32 out)
    pack_w<<<1536, 256, 0, stream>>>(proj_w, Wp, Cc, Cc);
    gemm_mfma<0, true, true><<<dim3(Mrows / 128, 8), 256, 0, stream>>>(
        P3, Wp, proj_b, x, nullptr, hb, Cc, Cc);
    // 6. y = RMS(h, ln2) -> bf16
    rms_bf16<<<Mrows, 256, 0, stream>>>(hb, ln2_w, P3);
    // 7. u = y @ up_w -> bf16 (P2)
    pack_w<<<6144, 256, 0, stream>>>(up_w, Wp, Cc, Ii);
    gemm_mfma<1, false, false><<<dim3(Mrows / 128, 32), 256, 0, stream>>>(
        P3, Wp, nullptr, nullptr, nullptr, P2, Cc, Ii);
    // 8. t = silu(y @ gate_w) * u -> bf16 (P1)
    pack_w<<<6144, 256, 0, stream>>>(gate_w, Wp, Cc, Ii);
    gemm_mfma<2, false, false><<<dim3(Mrows / 128, 32), 256, 0, stream>>>(
        P3, Wp, nullptr, nullptr, P2, P1, Cc, Ii);
    // 9. out = h + t @ down_w (fp32 out)
    pack_w<<<6144, 256, 0, stream>>>(down_w, Wp, Ii, Cc);
    gemm_mfma<0, false, true><<<dim3(Mrows / 128, 8), 256, 0, stream>>>(
        P1, Wp, nullptr, hb, nullptr, out, Ii, Cc);
}

// Round 5
// 386.390 us; speedup vs baseline: 16.8627x; 1.5224x over previous
//
#include <hip/hip_runtime.h>
#include <math.h>

// Problem constants (fixed by setup_inputs)
constexpr int Bb  = 2;
constexpr int Nn  = 1280;
constexpr int Cc  = 1024;
constexpr int Hh  = 16;
constexpr int DH  = 64;
constexpr int Ii  = 4096;
constexpr int Tt  = 256;    // text_len
constexpr int BSz = 128;    // block_size
constexpr int L1  = 4;      // len1
constexpr int Mrows = Bb * Nn;  // 2560

typedef __attribute__((ext_vector_type(8))) short short8v;
typedef __attribute__((ext_vector_type(4))) float f32x4;

__device__ __forceinline__ int segof(int n) {
    return n < Tt ? 0 : (n < Tt + L1 * BSz ? 1 : 2);
}
__device__ __forceinline__ unsigned short f2bf(float f) {
    unsigned int u = __float_as_uint(f);
    u += 0x7fffu + ((u >> 16) & 1u);        // RNE
    return (unsigned short)(u >> 16);
}
__device__ __forceinline__ float bf2f(unsigned short h) {
    return __uint_as_float(((unsigned int)h) << 16);
}

// ---------------------------------------------------------------------------
// RMSNorm fp32 -> bf16 out: one block per row, 256 threads, C=1024
// ---------------------------------------------------------------------------
__global__ __launch_bounds__(256)
void rms_bf16(const float* __restrict__ in, const float* __restrict__ w,
              unsigned short* __restrict__ out) {
    int row = blockIdx.x;
    int n   = row % Nn;
    int seg = segof(n);
    const float* x = in + (size_t)row * Cc;
    int t = threadIdx.x;
    float4 xv = reinterpret_cast<const float4*>(x)[t];
    float ss = xv.x * xv.x + xv.y * xv.y + xv.z * xv.z + xv.w * xv.w;
#pragma unroll
    for (int off = 32; off; off >>= 1) ss += __shfl_down(ss, off, 64);
    __shared__ float red[4];
    __shared__ float s_r;
    int lane = t & 63, wid = t >> 6;
    if (lane == 0) red[wid] = ss;
    __syncthreads();
    if (t == 0) s_r = rsqrtf((red[0] + red[1] + red[2] + red[3]) * (1.0f / Cc) + 1e-6f);
    __syncthreads();
    float r = s_r;
    float4 wv = reinterpret_cast<const float4*>(w + (size_t)seg * Cc)[t];
    ushort4 ov;
    ov.x = f2bf(wv.x * xv.x * r);
    ov.y = f2bf(wv.y * xv.y * r);
    ov.z = f2bf(wv.z * xv.z * r);
    ov.w = f2bf(wv.w * xv.w * r);
    *reinterpret_cast<ushort4*>(&out[(size_t)row * Cc + t * 4]) = ov;
}

// ---------------------------------------------------------------------------
// Pack fp32 weights [3][K][Nd] into fragment-linear bf16 layout
// ---------------------------------------------------------------------------
__global__ __launch_bounds__(256)
void pack_w(const float* __restrict__ W, unsigned short* __restrict__ PB,
            int K, int Nd) {
    size_t idx = (size_t)blockIdx.x * 256 + threadIdx.x;   // chunk id
    size_t cpseg = (size_t)K * Nd / 8;
    int s = (int)(idx / cpseg);
    size_t rm = idx % cpseg;
    int lane = (int)(rm & 63);
    int fr   = (int)((rm >> 6) & 7);
    size_t tile = rm >> 9;                  // kt*(Nd/128)+cb
    int nct = Nd >> 7;
    int cb = (int)(tile % nct);
    int kt = (int)(tile / nct);
    int col = cb * 128 + fr * 16 + (lane & 15);
    int k0  = kt * 32 + (lane >> 4) * 8;
    const float* src = W + ((size_t)s * K + k0) * Nd + col;
    unsigned short o[8];
#pragma unroll
    for (int j = 0; j < 8; j++) o[j] = f2bf(src[(size_t)j * Nd]);
    short8v v;
#pragma unroll
    for (int j = 0; j < 8; j++) v[j] = (short)o[j];
    *reinterpret_cast<short8v*>(&PB[idx * 8]) = v;
}

// ---------------------------------------------------------------------------
// bf16 MFMA GEMM: 128x128 tile, 256 thr (4 waves 2x2), BK=32, 16x16x32 MFMA.
// OUTMODE: 0 = f32 out, 1 = bf16 out, 2 = bf16 out with silu(acc)*U epilogue
// ---------------------------------------------------------------------------
template <int OUTMODE, bool BIAS, bool RES>
__global__ __launch_bounds__(256)
void gemm_mfma(const unsigned short* __restrict__ A,
               const unsigned short* __restrict__ PB,
               const float* __restrict__ bias, const float* __restrict__ res,
               const unsigned short* __restrict__ U, void* __restrict__ outp,
               int K, int Nd) {
    __shared__ __align__(16) unsigned short lds[8192];  // A frags, B frags
    int rb = blockIdx.x * 128, cb = blockIdx.y;
    int seg = segof(rb % Nn);
    int tid = threadIdx.x, lane = tid & 63, wid = tid >> 6;
    int wr = wid >> 1, wc = wid & 1;
    const unsigned short* PBseg = PB + (size_t)seg * K * Nd;
    const int nKt = K >> 5, nct = Nd >> 7;

    f32x4 acc[4][4];
#pragma unroll
    for (int i = 0; i < 4; i++)
#pragma unroll
        for (int j = 0; j < 4; j++) acc[i][j] = (f32x4){0.f, 0.f, 0.f, 0.f};

    for (int kt = 0; kt < nKt; ++kt) {
        short8v av[2], bv[2];
#pragma unroll
        for (int i = 0; i < 2; i++) {
            int c = tid + i * 256;          // chunk 0..511
            int mf = c >> 6, lc = c & 63;
            int row = rb + mf * 16 + (lc & 15);
            int k0  = kt * 32 + (lc >> 4) * 8;
            av[i] = *reinterpret_cast<const short8v*>(&A[(size_t)row * K + k0]);
            bv[i] = *reinterpret_cast<const short8v*>(
                &PBseg[((((size_t)kt * nct + cb) * 8 + mf) * 64 + lc) * 8]);
        }
        __syncthreads();                    // prev iteration's reads done
#pragma unroll
        for (int i = 0; i < 2; i++) {
            int c = tid + i * 256;
            *reinterpret_cast<short8v*>(&lds[(size_t)c * 8]) = av[i];
            *reinterpret_cast<short8v*>(&lds[4096 + (size_t)c * 8]) = bv[i];
        }
        __syncthreads();
        short8v afr[4], bfr[4];
#pragma unroll
        for (int m = 0; m < 4; m++)
            afr[m] = *reinterpret_cast<short8v*>(&lds[((wr * 4 + m) * 64 + lane) * 8]);
#pragma unroll
        for (int n = 0; n < 4; n++)
            bfr[n] = *reinterpret_cast<short8v*>(&lds[4096 + ((wc * 4 + n) * 64 + lane) * 8]);
#pragma unroll
        for (int m = 0; m < 4; m++)
#pragma unroll
            for (int n = 0; n < 4; n++)
                acc[m][n] = __builtin_amdgcn_mfma_f32_16x16x32_bf16(
                    afr[m], bfr[n], acc[m][n], 0, 0, 0);
    }

    // epilogue: C/D layout col=lane&15, row=(lane>>4)*4+r
    float* outf = (float*)outp;
    unsigned short* outh = (unsigned short*)outp;
#pragma unroll
    for (int n = 0; n < 4; n++) {
        int col = cb * 128 + wc * 64 + n * 16 + (lane & 15);
        float bvv = BIAS ? bias[(size_t)seg * Nd + col] : 0.f;
#pragma unroll
        for (int m = 0; m < 4; m++) {
#pragma unroll
            for (int r = 0; r < 4; r++) {
                int row = rb + wr * 64 + m * 16 + (lane >> 4) * 4 + r;
                float v = acc[m][n][r] + bvv;
                if (RES) v += res[(size_t)row * Nd + col];
                if (OUTMODE == 0) {
                    outf[(size_t)row * Nd + col] = v;
                } else if (OUTMODE == 1) {
                    outh[(size_t)row * Nd + col] = f2bf(v);
                } else {
                    float u = bf2f(U[(size_t)row * Nd + col]);
                    float t = v / (1.f + __expf(-v)) * u;
                    outh[(size_t)row * Nd + col] = f2bf(t);
                }
            }
        }
    }
}

// ---------------------------------------------------------------------------
// Split qkv(bf16) + per-head q/k RMSNorm + RoPE -> bf16 Q,K,V (bh, n, dh)
// ---------------------------------------------------------------------------
__global__ __launch_bounds__(256)
void split_rope(const unsigned short* __restrict__ qkv,
                const float* __restrict__ qn_w, const float* __restrict__ kn_w,
                const int* __restrict__ pos_ids, const int* __restrict__ tpos_ids,
                unsigned short* __restrict__ Q, unsigned short* __restrict__ K,
                unsigned short* __restrict__ V) {
    int row = blockIdx.x;   // b*N + n
    int b = row / Nn, n = row % Nn;
    int seg = segof(n);
    int lane = threadIdx.x & 63, wid = threadIdx.x >> 6;
    int pos = (n < Tt) ? tpos_ids[n] : pos_ids[n - Tt];
    int j = lane & 31;
    float ang = (float)pos * exp2f(-(float)j * (13.287712379549449f / 32.f));
    float cv = cosf(ang), sv = sinf(ang);
    float qw = qn_w[seg * DH + lane], kw = kn_w[seg * DH + lane];
    for (int h = wid; h < Hh; h += 4) {
        const unsigned short* base = qkv + (size_t)row * (3 * Cc) + h * DH + lane;
        float q = bf2f(base[0]), k = bf2f(base[Cc]), v = bf2f(base[2 * Cc]);
        float qs = q * q, ks = k * k;
#pragma unroll
        for (int off = 32; off; off >>= 1) {
            qs += __shfl_xor(qs, off, 64);
            ks += __shfl_xor(ks, off, 64);
        }
        q = q * rsqrtf(qs * (1.f / DH) + 1e-6f) * qw;
        k = k * rsqrtf(ks * (1.f / DH) + 1e-6f) * kw;
        float qp = __shfl_xor(q, 32, 64);
        float kp = __shfl_xor(k, 32, 64);
        float qo = q * cv + ((lane < 32) ? -qp * sv : qp * sv);
        float ko = k * cv + ((lane < 32) ? -kp * sv : kp * sv);
        size_t oidx = ((size_t)(b * Hh + h) * Nn + n) * DH + lane;
        Q[oidx] = f2bf(qo);
        K[oidx] = f2bf(ko);
        V[oidx] = f2bf(v);
    }
}

// ---------------------------------------------------------------------------
// MFMA flash attention. Block = (64-row q-tile, head), 4 waves; wave w owns
// q rows [q0+16w, q0+16w+16). Per visible 64-wide k-tile:
//   stage K [64ki][64dh] + V^T [64dh][64ki] in LDS (XOR-swizzled rows),
//   QK^T (8 MFMA) -> in-reg online softmax -> P to per-wave LDS (bf16,
//   swizzled) -> PV (8 MFMA) against V^T.
// Tile visibility is uniform per (q-tile, k-tile); only the text diagonal
// tile (kbase==q0<Tt) needs an elementwise causal mask.
// ---------------------------------------------------------------------------
__global__ __launch_bounds__(256)
void attn_mfma(const unsigned short* __restrict__ Qg,
               const unsigned short* __restrict__ Kg,
               const unsigned short* __restrict__ Vg,
               unsigned short* __restrict__ O) {
    __shared__ __align__(16) unsigned short k_lds[64 * 64];   // 8 KB
    __shared__ __align__(16) unsigned short vt_lds[64 * 64];  // 8 KB
    __shared__ __align__(16) unsigned short p_lds[4][16 * 64];// 8 KB

    int qt = blockIdx.x;
    int bh = blockIdx.y;
    int b = bh >> 4, h = bh & 15;
    int tid = threadIdx.x, lane = tid & 63, wid = tid >> 6;
    int g = lane >> 4, c = lane & 15;

    const size_t headoff = (size_t)bh * Nn * DH;
    int q0 = qt * 64;
    bool qtext = q0 < Tt;
    int qb = qtext ? 0 : (q0 - Tt) / BSz;

    // Q fragments (A-frag: row = lane&15, k = kb*32 + g*8 + j), held in regs
    int qrow_frag = q0 + wid * 16 + c;
    short8v aq[2];
#pragma unroll
    for (int kb = 0; kb < 2; kb++)
        aq[kb] = *reinterpret_cast<const short8v*>(
            &Qg[headoff + (size_t)qrow_frag * DH + kb * 32 + g * 8]);

    unsigned short* pbuf = &p_lds[wid][0];

    f32x4 o_[4];
#pragma unroll
    for (int nb = 0; nb < 4; nb++) o_[nb] = (f32x4){0.f, 0.f, 0.f, 0.f};
    float m_[4] = {-3.4e38f, -3.4e38f, -3.4e38f, -3.4e38f};
    float l_[4] = {0.f, 0.f, 0.f, 0.f};

    // staging indices: 256 thr, each 2x16B per tensor
    int tr = tid >> 2, tc = tid & 3;

    for (int kt = 0; kt < Nn / 64; kt++) {
        int kbase = kt * 64;
        bool vis, diag = false;
        if (qtext) {
            vis = (kbase <= q0);
            diag = (kbase == q0);
        } else if (kbase < Tt) {
            vis = true;
        } else {
            int kb = (kbase - Tt) / BSz;
            vis = (qb < L1) ? (kb <= qb)
                            : ((kb < L1 && qb - L1 > kb) || kb == qb);
        }
        if (!vis) continue;

        __syncthreads();   // previous tile's LDS reads complete
        // stage K tile [ki][dh], swizzle byte ^= (ki&7)<<4
        {
            const unsigned short* ks = &Kg[headoff + (size_t)(kbase + tr) * DH];
            const unsigned short* vs = &Vg[headoff + (size_t)(kbase + tr) * DH];
#pragma unroll
            for (int i = 0; i < 2; i++) {
                int ch = tc + i * 4;
                short8v kv = *reinterpret_cast<const short8v*>(ks + ch * 8);
                int byte = (tr * 128 + ch * 16) ^ ((tr & 7) << 4);
                *reinterpret_cast<short8v*>((char*)k_lds + byte) = kv;
                // V^T: element dh = ch*8+j goes to [dh][tr]
                short8v vv = *reinterpret_cast<const short8v*>(vs + ch * 8);
#pragma unroll
                for (int j = 0; j < 8; j++) {
                    int dh = ch * 8 + j;
                    int vbyte = (dh * 128 + tr * 2) ^ ((dh & 7) << 4);
                    *reinterpret_cast<unsigned short*>((char*)vt_lds + vbyte) =
                        (unsigned short)vv[j];
                }
            }
        }
        __syncthreads();

        // ---- QK^T ----
        f32x4 s_[4];
#pragma unroll
        for (int nb = 0; nb < 4; nb++) s_[nb] = (f32x4){0.f, 0.f, 0.f, 0.f};
#pragma unroll
        for (int nb = 0; nb < 4; nb++) {
            int kil = nb * 16 + c;
#pragma unroll
            for (int kb = 0; kb < 2; kb++) {
                int byte = (kil * 128 + kb * 64 + g * 16) ^ ((kil & 7) << 4);
                short8v bk = *reinterpret_cast<short8v*>((char*)k_lds + byte);
                s_[nb] = __builtin_amdgcn_mfma_f32_16x16x32_bf16(aq[kb], bk, s_[nb], 0, 0, 0);
            }
        }
        // scale + (diagonal-only) mask
#pragma unroll
        for (int nb = 0; nb < 4; nb++) {
#pragma unroll
            for (int r = 0; r < 4; r++) {
                float sv = s_[nb][r] * 0.125f;
                if (diag) {
                    int qrl = wid * 16 + g * 4 + r;     // local q row in 64-tile
                    int kcl = nb * 16 + c;              // local k col
                    if (qrl < kcl) sv = -3.4e38f;
                }
                s_[nb][r] = sv;
            }
        }
        // ---- online softmax (rows = g*4+r across 16 lanes c) ----
#pragma unroll
        for (int r = 0; r < 4; r++) {
            float mx = fmaxf(fmaxf(s_[0][r], s_[1][r]), fmaxf(s_[2][r], s_[3][r]));
#pragma unroll
            for (int off = 1; off <= 8; off <<= 1)
                mx = fmaxf(mx, __shfl_xor(mx, off, 64));
            float mn = fmaxf(m_[r], mx);
            float es = __expf(m_[r] - mn);
            m_[r] = mn;
            float pv[4];
            float rs = 0.f;
#pragma unroll
            for (int nb = 0; nb < 4; nb++) {
                pv[nb] = __expf(s_[nb][r] - mn);
                rs += pv[nb];
            }
#pragma unroll
            for (int off = 1; off <= 8; off <<= 1)
                rs += __shfl_xor(rs, off, 64);
            l_[r] = l_[r] * es + rs;
#pragma unroll
            for (int nb = 0; nb < 4; nb++) o_[nb][r] *= es;
            // write P row (bf16) to per-wave LDS, swizzled
            int qrl = g * 4 + r;
            int swz = (qrl & 7) << 4;
#pragma unroll
            for (int nb = 0; nb < 4; nb++) {
                int byte = (qrl * 128 + (nb * 16 + c) * 2) ^ swz;
                *reinterpret_cast<unsigned short*>((char*)pbuf + byte) = f2bf(pv[nb]);
            }
        }
        // ---- PV ----
        short8v aP[2];
#pragma unroll
        for (int kb = 0; kb < 2; kb++) {
            int byte = (c * 128 + kb * 64 + g * 16) ^ ((c & 7) << 4);
            aP[kb] = *reinterpret_cast<short8v*>((char*)pbuf + byte);
        }
#pragma unroll
        for (int nb = 0; nb < 4; nb++) {
            int dh = nb * 16 + c;
#pragma unroll
            for (int kb = 0; kb < 2; kb++) {
                int byte = (dh * 128 + kb * 64 + g * 16) ^ ((dh & 7) << 4);
                short8v bv = *reinterpret_cast<short8v*>((char*)vt_lds + byte);
                o_[nb] = __builtin_amdgcn_mfma_f32_16x16x32_bf16(aP[kb], bv, o_[nb], 0, 0, 0);
            }
        }
    }

    // ---- normalize + write O (B, N, C) bf16 ----
    float inv_[4];
#pragma unroll
    for (int r = 0; r < 4; r++) inv_[r] = 1.f / l_[r];
#pragma unroll
    for (int nb = 0; nb < 4; nb++) {
        int col = h * DH + nb * 16 + c;
#pragma unroll
        for (int r = 0; r < 4; r++) {
            int row = q0 + wid * 16 + g * 4 + r;
            O[((size_t)b * Nn + row) * Cc + col] = f2bf(o_[nb][r] * inv_[r]);
        }
    }
}

// ---------------------------------------------------------------------------
// kernel_launch
// ---------------------------------------------------------------------------
extern "C" void kernel_launch(void* const* d_in, const int* in_sizes, int n_in,
                              void* d_out, int out_size, void* d_ws, size_t ws_size,
                              hipStream_t stream) {
    const float* x        = (const float*)d_in[0];
    const int*   pos_ids  = (const int*)d_in[1];
    const int*   tpos_ids = (const int*)d_in[2];
    const float* qkv_w    = (const float*)d_in[3];
    const float* qkv_b    = (const float*)d_in[4];
    const float* proj_w   = (const float*)d_in[5];
    const float* proj_b   = (const float*)d_in[6];
    const float* qn_w     = (const float*)d_in[7];
    const float* kn_w     = (const float*)d_in[8];
    const float* ln1_w    = (const float*)d_in[9];
    const float* ln2_w    = (const float*)d_in[10];
    const float* gate_w   = (const float*)d_in[11];
    const float* up_w     = (const float*)d_in[12];
    const float* down_w   = (const float*)d_in[13];
    float* out = (float*)d_out;
    char*  wsb = (char*)d_ws;

    // workspace regions (bytes)
    unsigned short* Wp   = (unsigned short*)(wsb);              // 25.2 MB packed weights
    unsigned short* P1   = (unsigned short*)(wsb + 25165824);   // qkvbf / tbf (20.97 MB)
    unsigned short* P2   = (unsigned short*)(wsb + 46137344);   // Q,K,V bf16 / ubf (20.97 MB)
    unsigned short* P3   = (unsigned short*)(wsb + 67108864);   // xnbf/obf/ybf (5.24 MB)
    float*          hb   = (float*)(wsb + 72351744);            // 10.49 MB fp32
    unsigned short* Qbf  = P2;
    unsigned short* Kbf  = P2 + 2621440;
    unsigned short* Vbf  = P2 + 5242880;

    // 1. xn = RMS(x, ln1) -> bf16
    rms_bf16<<<Mrows, 256, 0, stream>>>(x, ln1_w, P3);
    // 2. pack qkv weights; qkv GEMM -> bf16
    pack_w<<<4608, 256, 0, stream>>>(qkv_w, Wp, Cc, 3 * Cc);
    gemm_mfma<1, true, false><<<dim3(Mrows / 128, 24), 256, 0, stream>>>(
        P3, Wp, qkv_b, nullptr, nullptr, P1, Cc, 3 * Cc);
    // 3. split + q/k RMS + RoPE (bf16)
    split_rope<<<Mrows, 256, 0, stream>>>(P1, qn_w, kn_w, pos_ids, tpos_ids,
                                          Qbf, Kbf, Vbf);
    // 4. attention -> obf (bf16, (B,N,C))
    attn_mfma<<<dim3(Nn / 64, Bb * Hh), 256, 0, stream>>>(Qbf, Kbf, Vbf, P3);
    // 5. h = x + o @ proj_w + proj_b  (fp32 out)
    pack_w<<<1536, 256, 0, stream>>>(proj_w, Wp, Cc, Cc);
    gemm_mfma<0, true, true><<<dim3(Mrows / 128, 8), 256, 0, stream>>>(
        P3, Wp, proj_b, x, nullptr, hb, Cc, Cc);
    // 6. y = RMS(h, ln2) -> bf16
    rms_bf16<<<Mrows, 256, 0, stream>>>(hb, ln2_w, P3);
    // 7. u = y @ up_w -> bf16 (P2)
    pack_w<<<6144, 256, 0, stream>>>(up_w, Wp, Cc, Ii);
    gemm_mfma<1, false, false><<<dim3(Mrows / 128, 32), 256, 0, stream>>>(
        P3, Wp, nullptr, nullptr, nullptr, P2, Cc, Ii);
    // 8. t = silu(y @ gate_w) * u -> bf16 (P1)
    pack_w<<<6144, 256, 0, stream>>>(gate_w, Wp, Cc, Ii);
    gemm_mfma<2, false, false><<<dim3(Mrows / 128, 32), 256, 0, stream>>>(
        P3, Wp, nullptr, nullptr, P2, P1, Cc, Ii);
    // 9. out = h + t @ down_w (fp32 out)
    pack_w<<<6144, 256, 0, stream>>>(down_w, Wp, Ii, Cc);
    gemm_mfma<0, false, true><<<dim3(Mrows / 128, 8), 256, 0, stream>>>(
        P1, Wp, nullptr, hb, nullptr, out, Ii, Cc);
}

// Round 6
// 306.651 us; speedup vs baseline: 21.2476x; 1.2600x over previous
//
#include <hip/hip_runtime.h>
#include <math.h>

// Problem constants (fixed by setup_inputs)
constexpr int Bb  = 2;
constexpr int Nn  = 1280;
constexpr int Cc  = 1024;
constexpr int Hh  = 16;
constexpr int DH  = 64;
constexpr int Ii  = 4096;
constexpr int Tt  = 256;    // text_len
constexpr int BSz = 128;    // block_size
constexpr int L1  = 4;      // len1
constexpr int Mrows = Bb * Nn;  // 2560

typedef __attribute__((ext_vector_type(8))) short short8v;
typedef __attribute__((ext_vector_type(4))) float f32x4;

__device__ __forceinline__ int segof(int n) {
    return n < Tt ? 0 : (n < Tt + L1 * BSz ? 1 : 2);
}
__device__ __forceinline__ unsigned short f2bf(float f) {
    unsigned int u = __float_as_uint(f);
    u += 0x7fffu + ((u >> 16) & 1u);        // RNE
    return (unsigned short)(u >> 16);
}
__device__ __forceinline__ float bf2f(unsigned short h) {
    return __uint_as_float(((unsigned int)h) << 16);
}

// ---------------------------------------------------------------------------
// RMSNorm fp32 -> bf16 out: one block per row, 256 threads, C=1024
// ---------------------------------------------------------------------------
__global__ __launch_bounds__(256)
void rms_bf16(const float* __restrict__ in, const float* __restrict__ w,
              unsigned short* __restrict__ out) {
    int row = blockIdx.x;
    int n   = row % Nn;
    int seg = segof(n);
    const float* x = in + (size_t)row * Cc;
    int t = threadIdx.x;
    float4 xv = reinterpret_cast<const float4*>(x)[t];
    float ss = xv.x * xv.x + xv.y * xv.y + xv.z * xv.z + xv.w * xv.w;
#pragma unroll
    for (int off = 32; off; off >>= 1) ss += __shfl_down(ss, off, 64);
    __shared__ float red[4];
    __shared__ float s_r;
    int lane = t & 63, wid = t >> 6;
    if (lane == 0) red[wid] = ss;
    __syncthreads();
    if (t == 0) s_r = rsqrtf((red[0] + red[1] + red[2] + red[3]) * (1.0f / Cc) + 1e-6f);
    __syncthreads();
    float r = s_r;
    float4 wv = reinterpret_cast<const float4*>(w + (size_t)seg * Cc)[t];
    ushort4 ov;
    ov.x = f2bf(wv.x * xv.x * r);
    ov.y = f2bf(wv.y * xv.y * r);
    ov.z = f2bf(wv.z * xv.z * r);
    ov.w = f2bf(wv.w * xv.w * r);
    *reinterpret_cast<ushort4*>(&out[(size_t)row * Cc + t * 4]) = ov;
}

// ---------------------------------------------------------------------------
// Pack fp32 weights [3][K][Nd] into fragment-linear bf16 layout:
// chunk (kt32, cb, fr, lane) holds 8 bf16: element j =
//   W[seg][kt32*32 + (lane>>4)*8 + j][cb*128 + fr*16 + (lane&15)]
// ---------------------------------------------------------------------------
__global__ __launch_bounds__(256)
void pack_w(const float* __restrict__ W, unsigned short* __restrict__ PB,
            int K, int Nd) {
    size_t idx = (size_t)blockIdx.x * 256 + threadIdx.x;   // chunk id
    size_t cpseg = (size_t)K * Nd / 8;
    int s = (int)(idx / cpseg);
    size_t rm = idx % cpseg;
    int lane = (int)(rm & 63);
    int fr   = (int)((rm >> 6) & 7);
    size_t tile = rm >> 9;                  // kt32*(Nd/128)+cb
    int nct = Nd >> 7;
    int cb = (int)(tile % nct);
    int kt = (int)(tile / nct);
    int col = cb * 128 + fr * 16 + (lane & 15);
    int k0  = kt * 32 + (lane >> 4) * 8;
    const float* src = W + ((size_t)s * K + k0) * Nd + col;
    unsigned short o[8];
#pragma unroll
    for (int j = 0; j < 8; j++) o[j] = f2bf(src[(size_t)j * Nd]);
    short8v v;
#pragma unroll
    for (int j = 0; j < 8; j++) v[j] = (short)o[j];
    *reinterpret_cast<short8v*>(&PB[idx * 8]) = v;
}

// ---------------------------------------------------------------------------
// bf16 MFMA GEMM v2: 64x128 tile, BK=64, 256 thr (4 waves 2x2: wave = 32x64),
// prefetched reg-staging (loads for kt+1 issued under MFMA of kt).
// OUTMODE: 0 = f32 out, 1 = bf16 out, 2 = bf16 silu(acc)*U epilogue.
// SPLIT: gridDim.z=2 halves of K, f32 partial out at z*Mrows*Nd.
// ---------------------------------------------------------------------------
template <int OUTMODE, bool BIAS, bool RES, bool SPLIT>
__global__ __launch_bounds__(256)
void gemm64(const unsigned short* __restrict__ A,
            const unsigned short* __restrict__ PB,
            const float* __restrict__ bias, const float* __restrict__ res,
            const unsigned short* __restrict__ U, void* __restrict__ outp,
            int K, int Nd) {
    __shared__ __align__(16) unsigned short lds[12288];  // A 8KB | B 16KB
    int rb = blockIdx.x * 64, cb = blockIdx.y;
    int seg = segof(rb % Nn);
    int tid = threadIdx.x, lane = tid & 63, wid = tid >> 6;
    int wr = wid >> 1, wc = wid & 1;
    int g = lane >> 4, c_ = lane & 15;
    const unsigned short* PBseg = PB + (size_t)seg * K * Nd;
    const int nct = Nd >> 7;
    const int Keff = SPLIT ? (K >> 1) : K;
    const int nKt = Keff >> 6;
    const int kz = SPLIT ? blockIdx.z * Keff : 0;

    f32x4 acc[2][4];
#pragma unroll
    for (int m = 0; m < 2; m++)
#pragma unroll
        for (int n = 0; n < 4; n++) acc[m][n] = (f32x4){0.f, 0.f, 0.f, 0.f};

    short8v av[2], bv[4];
    auto load_tile = [&](int kt) {
#pragma unroll
        for (int i = 0; i < 2; i++) {
            int c = tid + i * 256;              // 0..511
            int rf = c >> 7, kb = (c >> 6) & 1, lc = c & 63;
            int row = rb + rf * 16 + (lc & 15);
            int k0  = kz + kt * 64 + kb * 32 + (lc >> 4) * 8;
            av[i] = *reinterpret_cast<const short8v*>(&A[(size_t)row * K + k0]);
        }
#pragma unroll
        for (int i = 0; i < 4; i++) {
            int c = tid + i * 256;              // 0..1023
            int cf = c >> 7, kb = (c >> 6) & 1, lc = c & 63;
            int kt32 = (kz >> 5) + kt * 2 + kb;
            bv[i] = *reinterpret_cast<const short8v*>(
                &PBseg[((((size_t)kt32 * nct + cb) * 8 + cf) * 64 + lc) * 8]);
        }
    };

    load_tile(0);
    for (int kt = 0; kt < nKt; ++kt) {
        __syncthreads();                        // prev iter's ds_reads done
#pragma unroll
        for (int i = 0; i < 2; i++)
            *reinterpret_cast<short8v*>(&lds[(size_t)(tid + i * 256) * 8]) = av[i];
#pragma unroll
        for (int i = 0; i < 4; i++)
            *reinterpret_cast<short8v*>(&lds[4096 + (size_t)(tid + i * 256) * 8]) = bv[i];
        __syncthreads();
        if (kt + 1 < nKt) load_tile(kt + 1);    // in flight under MFMA
        short8v afr[2][2], bfr[4][2];
#pragma unroll
        for (int m = 0; m < 2; m++)
#pragma unroll
            for (int kb = 0; kb < 2; kb++)
                afr[m][kb] = *reinterpret_cast<short8v*>(
                    &lds[(((wr * 2 + m) * 2 + kb) * 64 + lane) * 8]);
#pragma unroll
        for (int n = 0; n < 4; n++)
#pragma unroll
            for (int kb = 0; kb < 2; kb++)
                bfr[n][kb] = *reinterpret_cast<short8v*>(
                    &lds[4096 + (((wc * 4 + n) * 2 + kb) * 64 + lane) * 8]);
#pragma unroll
        for (int m = 0; m < 2; m++)
#pragma unroll
            for (int n = 0; n < 4; n++)
#pragma unroll
                for (int kb = 0; kb < 2; kb++)
                    acc[m][n] = __builtin_amdgcn_mfma_f32_16x16x32_bf16(
                        afr[m][kb], bfr[n][kb], acc[m][n], 0, 0, 0);
    }

    // epilogue: C/D layout col=lane&15, row=(lane>>4)*4+r
    float* outf = (float*)outp;
    unsigned short* outh = (unsigned short*)outp;
    size_t zoff = SPLIT ? (size_t)blockIdx.z * Mrows * Nd : 0;
#pragma unroll
    for (int n = 0; n < 4; n++) {
        int col = cb * 128 + wc * 64 + n * 16 + c_;
        float bvv = BIAS ? bias[(size_t)seg * Nd + col] : 0.f;
#pragma unroll
        for (int m = 0; m < 2; m++) {
#pragma unroll
            for (int r = 0; r < 4; r++) {
                int row = rb + wr * 32 + m * 16 + g * 4 + r;
                float v = acc[m][n][r] + bvv;
                if (RES) v += res[(size_t)row * Nd + col];
                if (OUTMODE == 0) {
                    outf[zoff + (size_t)row * Nd + col] = v;
                } else if (OUTMODE == 1) {
                    outh[(size_t)row * Nd + col] = f2bf(v);
                } else {
                    float u = bf2f(U[(size_t)row * Nd + col]);
                    float t = v / (1.f + __expf(-v)) * u;
                    outh[(size_t)row * Nd + col] = f2bf(t);
                }
            }
        }
    }
}

// ---------------------------------------------------------------------------
// combine down-GEMM split-K partials + residual: out = hb + p0 + p1
// ---------------------------------------------------------------------------
__global__ __launch_bounds__(256)
void combine_down(const float* __restrict__ hb, const float* __restrict__ p,
                  float* __restrict__ out) {
    int i = blockIdx.x * 256 + threadIdx.x;     // float4 index
    const float4* h4 = (const float4*)hb;
    const float4* p4 = (const float4*)p;
    float4 a = h4[i], b0 = p4[i], b1 = p4[i + (Mrows * Cc / 4)];
    float4 r;
    r.x = a.x + b0.x + b1.x;
    r.y = a.y + b0.y + b1.y;
    r.z = a.z + b0.z + b1.z;
    r.w = a.w + b0.w + b1.w;
    reinterpret_cast<float4*>(out)[i] = r;
}

// ---------------------------------------------------------------------------
// Split qkv(bf16) + per-head q/k RMSNorm + RoPE -> bf16 Q,K,V (bh, n, dh)
// ---------------------------------------------------------------------------
__global__ __launch_bounds__(256)
void split_rope(const unsigned short* __restrict__ qkv,
                const float* __restrict__ qn_w, const float* __restrict__ kn_w,
                const int* __restrict__ pos_ids, const int* __restrict__ tpos_ids,
                unsigned short* __restrict__ Q, unsigned short* __restrict__ K,
                unsigned short* __restrict__ V) {
    int row = blockIdx.x;   // b*N + n
    int b = row / Nn, n = row % Nn;
    int seg = segof(n);
    int lane = threadIdx.x & 63, wid = threadIdx.x >> 6;
    int pos = (n < Tt) ? tpos_ids[n] : pos_ids[n - Tt];
    int j = lane & 31;
    float ang = (float)pos * exp2f(-(float)j * (13.287712379549449f / 32.f));
    float cv = cosf(ang), sv = sinf(ang);
    float qw = qn_w[seg * DH + lane], kw = kn_w[seg * DH + lane];
    for (int h = wid; h < Hh; h += 4) {
        const unsigned short* base = qkv + (size_t)row * (3 * Cc) + h * DH + lane;
        float q = bf2f(base[0]), k = bf2f(base[Cc]), v = bf2f(base[2 * Cc]);
        float qs = q * q, ks = k * k;
#pragma unroll
        for (int off = 32; off; off >>= 1) {
            qs += __shfl_xor(qs, off, 64);
            ks += __shfl_xor(ks, off, 64);
        }
        q = q * rsqrtf(qs * (1.f / DH) + 1e-6f) * qw;
        k = k * rsqrtf(ks * (1.f / DH) + 1e-6f) * kw;
        float qp = __shfl_xor(q, 32, 64);
        float kp = __shfl_xor(k, 32, 64);
        float qo = q * cv + ((lane < 32) ? -qp * sv : qp * sv);
        float ko = k * cv + ((lane < 32) ? -kp * sv : kp * sv);
        size_t oidx = ((size_t)(b * Hh + h) * Nn + n) * DH + lane;
        Q[oidx] = f2bf(qo);
        K[oidx] = f2bf(ko);
        V[oidx] = f2bf(v);
    }
}

// ---------------------------------------------------------------------------
// MFMA flash attention (unchanged from round 5 — verified)
// ---------------------------------------------------------------------------
__global__ __launch_bounds__(256)
void attn_mfma(const unsigned short* __restrict__ Qg,
               const unsigned short* __restrict__ Kg,
               const unsigned short* __restrict__ Vg,
               unsigned short* __restrict__ O) {
    __shared__ __align__(16) unsigned short k_lds[64 * 64];   // 8 KB
    __shared__ __align__(16) unsigned short vt_lds[64 * 64];  // 8 KB
    __shared__ __align__(16) unsigned short p_lds[4][16 * 64];// 8 KB

    int qt = blockIdx.x;
    int bh = blockIdx.y;
    int b = bh >> 4, h = bh & 15;
    int tid = threadIdx.x, lane = tid & 63, wid = tid >> 6;
    int g = lane >> 4, c = lane & 15;

    const size_t headoff = (size_t)bh * Nn * DH;
    int q0 = qt * 64;
    bool qtext = q0 < Tt;
    int qb = qtext ? 0 : (q0 - Tt) / BSz;

    int qrow_frag = q0 + wid * 16 + c;
    short8v aq[2];
#pragma unroll
    for (int kb = 0; kb < 2; kb++)
        aq[kb] = *reinterpret_cast<const short8v*>(
            &Qg[headoff + (size_t)qrow_frag * DH + kb * 32 + g * 8]);

    unsigned short* pbuf = &p_lds[wid][0];

    f32x4 o_[4];
#pragma unroll
    for (int nb = 0; nb < 4; nb++) o_[nb] = (f32x4){0.f, 0.f, 0.f, 0.f};
    float m_[4] = {-3.4e38f, -3.4e38f, -3.4e38f, -3.4e38f};
    float l_[4] = {0.f, 0.f, 0.f, 0.f};

    int tr = tid >> 2, tc = tid & 3;

    for (int kt = 0; kt < Nn / 64; kt++) {
        int kbase = kt * 64;
        bool vis, diag = false;
        if (qtext) {
            vis = (kbase <= q0);
            diag = (kbase == q0);
        } else if (kbase < Tt) {
            vis = true;
        } else {
            int kb = (kbase - Tt) / BSz;
            vis = (qb < L1) ? (kb <= qb)
                            : ((kb < L1 && qb - L1 > kb) || kb == qb);
        }
        if (!vis) continue;

        __syncthreads();
        {
            const unsigned short* ks = &Kg[headoff + (size_t)(kbase + tr) * DH];
            const unsigned short* vs = &Vg[headoff + (size_t)(kbase + tr) * DH];
#pragma unroll
            for (int i = 0; i < 2; i++) {
                int ch = tc + i * 4;
                short8v kv = *reinterpret_cast<const short8v*>(ks + ch * 8);
                int byte = (tr * 128 + ch * 16) ^ ((tr & 7) << 4);
                *reinterpret_cast<short8v*>((char*)k_lds + byte) = kv;
                short8v vv = *reinterpret_cast<const short8v*>(vs + ch * 8);
#pragma unroll
                for (int j = 0; j < 8; j++) {
                    int dh = ch * 8 + j;
                    int vbyte = (dh * 128 + tr * 2) ^ ((dh & 7) << 4);
                    *reinterpret_cast<unsigned short*>((char*)vt_lds + vbyte) =
                        (unsigned short)vv[j];
                }
            }
        }
        __syncthreads();

        f32x4 s_[4];
#pragma unroll
        for (int nb = 0; nb < 4; nb++) s_[nb] = (f32x4){0.f, 0.f, 0.f, 0.f};
#pragma unroll
        for (int nb = 0; nb < 4; nb++) {
            int kil = nb * 16 + c;
#pragma unroll
            for (int kb = 0; kb < 2; kb++) {
                int byte = (kil * 128 + kb * 64 + g * 16) ^ ((kil & 7) << 4);
                short8v bk = *reinterpret_cast<short8v*>((char*)k_lds + byte);
                s_[nb] = __builtin_amdgcn_mfma_f32_16x16x32_bf16(aq[kb], bk, s_[nb], 0, 0, 0);
            }
        }
#pragma unroll
        for (int nb = 0; nb < 4; nb++) {
#pragma unroll
            for (int r = 0; r < 4; r++) {
                float sv = s_[nb][r] * 0.125f;
                if (diag) {
                    int qrl = wid * 16 + g * 4 + r;
                    int kcl = nb * 16 + c;
                    if (qrl < kcl) sv = -3.4e38f;
                }
                s_[nb][r] = sv;
            }
        }
#pragma unroll
        for (int r = 0; r < 4; r++) {
            float mx = fmaxf(fmaxf(s_[0][r], s_[1][r]), fmaxf(s_[2][r], s_[3][r]));
#pragma unroll
            for (int off = 1; off <= 8; off <<= 1)
                mx = fmaxf(mx, __shfl_xor(mx, off, 64));
            float mn = fmaxf(m_[r], mx);
            float es = __expf(m_[r] - mn);
            m_[r] = mn;
            float pv[4];
            float rs = 0.f;
#pragma unroll
            for (int nb = 0; nb < 4; nb++) {
                pv[nb] = __expf(s_[nb][r] - mn);
                rs += pv[nb];
            }
#pragma unroll
            for (int off = 1; off <= 8; off <<= 1)
                rs += __shfl_xor(rs, off, 64);
            l_[r] = l_[r] * es + rs;
#pragma unroll
            for (int nb = 0; nb < 4; nb++) o_[nb][r] *= es;
            int qrl = g * 4 + r;
            int swz = (qrl & 7) << 4;
#pragma unroll
            for (int nb = 0; nb < 4; nb++) {
                int byte = (qrl * 128 + (nb * 16 + c) * 2) ^ swz;
                *reinterpret_cast<unsigned short*>((char*)pbuf + byte) = f2bf(pv[nb]);
            }
        }
        short8v aP[2];
#pragma unroll
        for (int kb = 0; kb < 2; kb++) {
            int byte = (c * 128 + kb * 64 + g * 16) ^ ((c & 7) << 4);
            aP[kb] = *reinterpret_cast<short8v*>((char*)pbuf + byte);
        }
#pragma unroll
        for (int nb = 0; nb < 4; nb++) {
            int dh = nb * 16 + c;
#pragma unroll
            for (int kb = 0; kb < 2; kb++) {
                int byte = (dh * 128 + kb * 64 + g * 16) ^ ((dh & 7) << 4);
                short8v bv = *reinterpret_cast<short8v*>((char*)vt_lds + byte);
                o_[nb] = __builtin_amdgcn_mfma_f32_16x16x32_bf16(aP[kb], bv, o_[nb], 0, 0, 0);
            }
        }
    }

    float inv_[4];
#pragma unroll
    for (int r = 0; r < 4; r++) inv_[r] = 1.f / l_[r];
#pragma unroll
    for (int nb = 0; nb < 4; nb++) {
        int col = h * DH + nb * 16 + c;
#pragma unroll
        for (int r = 0; r < 4; r++) {
            int row = q0 + wid * 16 + g * 4 + r;
            O[((size_t)b * Nn + row) * Cc + col] = f2bf(o_[nb][r] * inv_[r]);
        }
    }
}

// ---------------------------------------------------------------------------
// kernel_launch
// ---------------------------------------------------------------------------
extern "C" void kernel_launch(void* const* d_in, const int* in_sizes, int n_in,
                              void* d_out, int out_size, void* d_ws, size_t ws_size,
                              hipStream_t stream) {
    const float* x        = (const float*)d_in[0];
    const int*   pos_ids  = (const int*)d_in[1];
    const int*   tpos_ids = (const int*)d_in[2];
    const float* qkv_w    = (const float*)d_in[3];
    const float* qkv_b    = (const float*)d_in[4];
    const float* proj_w   = (const float*)d_in[5];
    const float* proj_b   = (const float*)d_in[6];
    const float* qn_w     = (const float*)d_in[7];
    const float* kn_w     = (const float*)d_in[8];
    const float* ln1_w    = (const float*)d_in[9];
    const float* ln2_w    = (const float*)d_in[10];
    const float* gate_w   = (const float*)d_in[11];
    const float* up_w     = (const float*)d_in[12];
    const float* down_w   = (const float*)d_in[13];
    float* out = (float*)d_out;
    char*  wsb = (char*)d_ws;

    // workspace regions (bytes)
    unsigned short* Wp   = (unsigned short*)(wsb);              // 25.2 MB packed weights
    unsigned short* P1   = (unsigned short*)(wsb + 25165824);   // qkvbf / tbf (20.97 MB)
    unsigned short* P2   = (unsigned short*)(wsb + 46137344);   // QKV bf16 / u / down partials
    unsigned short* P3   = (unsigned short*)(wsb + 67108864);   // xnbf/obf/ybf (5.24 MB)
    float*          hb   = (float*)(wsb + 72351744);            // 10.49 MB fp32
    unsigned short* Qbf  = P2;
    unsigned short* Kbf  = P2 + 2621440;
    unsigned short* Vbf  = P2 + 5242880;
    float*          Pd   = (float*)P2;                          // down partials (2x10.5MB)

    // 1. xn = RMS(x, ln1) -> bf16
    rms_bf16<<<Mrows, 256, 0, stream>>>(x, ln1_w, P3);
    // 2. pack qkv weights; qkv GEMM -> bf16
    pack_w<<<4608, 256, 0, stream>>>(qkv_w, Wp, Cc, 3 * Cc);
    gemm64<1, true, false, false><<<dim3(Mrows / 64, 24), 256, 0, stream>>>(
        P3, Wp, qkv_b, nullptr, nullptr, P1, Cc, 3 * Cc);
    // 3. split + q/k RMS + RoPE (bf16)
    split_rope<<<Mrows, 256, 0, stream>>>(P1, qn_w, kn_w, pos_ids, tpos_ids,
                                          Qbf, Kbf, Vbf);
    // 4. attention -> obf (bf16, (B,N,C))
    attn_mfma<<<dim3(Nn / 64, Bb * Hh), 256, 0, stream>>>(Qbf, Kbf, Vbf, P3);
    // 5. h = x + o @ proj_w + proj_b  (fp32 out)
    pack_w<<<1536, 256, 0, stream>>>(proj_w, Wp, Cc, Cc);
    gemm64<0, true, true, false><<<dim3(Mrows / 64, 8), 256, 0, stream>>>(
        P3, Wp, proj_b, x, nullptr, hb, Cc, Cc);
    // 6. y = RMS(h, ln2) -> bf16
    rms_bf16<<<Mrows, 256, 0, stream>>>(hb, ln2_w, P3);
    // 7. u = y @ up_w -> bf16 (P2)
    pack_w<<<6144, 256, 0, stream>>>(up_w, Wp, Cc, Ii);
    gemm64<1, false, false, false><<<dim3(Mrows / 64, 32), 256, 0, stream>>>(
        P3, Wp, nullptr, nullptr, nullptr, P2, Cc, Ii);
    // 8. t = silu(y @ gate_w) * u -> bf16 (P1)
    pack_w<<<6144, 256, 0, stream>>>(gate_w, Wp, Cc, Ii);
    gemm64<2, false, false, false><<<dim3(Mrows / 64, 32), 256, 0, stream>>>(
        P3, Wp, nullptr, nullptr, P2, P1, Cc, Ii);
    // 9. down partials (split-K=2) -> Pd ; then out = hb + p0 + p1
    pack_w<<<6144, 256, 0, stream>>>(down_w, Wp, Ii, Cc);
    gemm64<0, false, false, true><<<dim3(Mrows / 64, 8, 2), 256, 0, stream>>>(
        P1, Wp, nullptr, nullptr, nullptr, Pd, Ii, Cc);
    combine_down<<<Mrows * Cc / 1024, 256, 0, stream>>>(hb, Pd, out);
}